// Round 8
// baseline (1414.190 us; speedup 1.0000x reference)
//
#include <hip/hip_runtime.h>

#define Adim 4096
#define HD 128
#define TSTEPS 30
#define NROWS 24576
#define RBLK 32
#define NBLKS 768           // all resident: 3 blocks/CU target
#define DT_C 0.2f
#define SQDT_C 0.44721359549995794f
#define LN_EPS 1e-5f

#define PI_OFF   2949120    // 6*4096*30*4
#define MASK_OFF 2973696    // PI_OFF + 24576

typedef unsigned short u16;
typedef __bf16 bf16x8 __attribute__((ext_vector_type(8)));
typedef float f32x4 __attribute__((ext_vector_type(4)));

__device__ __forceinline__ u16 f2bf(float x){
    unsigned u = __builtin_bit_cast(unsigned, x);
    u = (u + 0x7fffu + ((u >> 16) & 1u)) >> 16;
    return (u16)u;
}
__device__ __forceinline__ float bf2f(unsigned h){
    unsigned u = (h & 0xffffu) << 16;
    return __builtin_bit_cast(float, u);
}
__device__ __forceinline__ unsigned pack2(float a, float b){
    unsigned r;
    asm("v_cvt_pk_bf16_f32 %0, %1, %2" : "=v"(r) : "v"(a), "v"(b));
    return r;
}
__device__ __forceinline__ float tanh_f(float x){
    return 1.0f - 2.0f / (1.0f + __expf(2.0f * x));
}
__device__ __forceinline__ float sigm_f(float x){
    return 1.0f / (1.0f + __expf(-x));
}
#define SWZ(r,k) ((k) ^ (((r)&7)<<3))
#define MFMA(A,B,C) __builtin_amdgcn_mfma_f32_16x16x32_bf16(A, B, C, 0, 0, 0)

// ---- load this wave's weight a-frags (16 output channels) from L2-hot image ----
__device__ __forceinline__ void loadW(const u16* __restrict__ img, int lane, int wid,
                                      bf16x8 W[4]) {
    const int c = wid*16 + (lane & 15);
    const int kq = lane >> 4;
#pragma unroll
    for (int kk = 0; kk < 4; ++kk)
        W[kk] = *reinterpret_cast<const bf16x8*>(img + c*HD + SWZ(c, kk*32 + kq*8));
}

// ---- GEMMs (swapped): D[c][r] = sum_k W[c][k] act[r][k]; 32 rows = 2 tiles ----
__device__ __forceinline__ void gemm1(const u16* __restrict__ act, const bf16x8 (&W)[4],
                                      int lane, f32x4 acc[2]) {
    const int rl = lane & 15, kq = lane >> 4;
#pragma unroll
    for (int tr = 0; tr < 2; ++tr) {
        const int r = tr*16 + rl;
        const u16* arow = act + r*HD;
        f32x4 a = {0.f,0.f,0.f,0.f};
#pragma unroll
        for (int kk = 0; kk < 4; ++kk) {
            bf16x8 bf = *reinterpret_cast<const bf16x8*>(arow + SWZ(r, kk*32 + kq*8));
            a = MFMA(W[kk], bf, a);
        }
        acc[tr] = a;
    }
}
__device__ __forceinline__ void gemm2(const u16* __restrict__ act,
                                      const bf16x8 (&Wx)[4], const bf16x8 (&Wy)[4],
                                      int lane, f32x4 accX[2], f32x4 accY[2]) {
    const int rl = lane & 15, kq = lane >> 4;
#pragma unroll
    for (int tr = 0; tr < 2; ++tr) {
        const int r = tr*16 + rl;
        const u16* arow = act + r*HD;
        f32x4 ax = {0.f,0.f,0.f,0.f}, ay = {0.f,0.f,0.f,0.f};
#pragma unroll
        for (int kk = 0; kk < 4; ++kk) {
            bf16x8 bf = *reinterpret_cast<const bf16x8*>(arow + SWZ(r, kk*32 + kq*8));
            ax = MFMA(Wx[kk], bf, ax);
            ay = MFMA(Wy[kk], bf, ay);
        }
        accX[tr] = ax; accY[tr] = ay;
    }
}

// ---- epilogues ----
__device__ __forceinline__ void epiT(const f32x4 acc[2], const float b[4],
                                     u16* dst, int lane, int wid) {
    const int c0 = wid*16 + ((lane>>4)<<2);
    const int rl = lane & 15;
#pragma unroll
    for (int tr = 0; tr < 2; ++tr) {
        int r = tr*16 + rl;
        float v0 = tanh_f(acc[tr][0] + b[0]);
        float v1 = tanh_f(acc[tr][1] + b[1]);
        float v2 = tanh_f(acc[tr][2] + b[2]);
        float v3 = tanh_f(acc[tr][3] + b[3]);
        uint2 pk = { pack2(v0, v1), pack2(v2, v3) };
        *reinterpret_cast<uint2*>(dst + r*HD + SWZ(r, c0)) = pk;
    }
}
__device__ __forceinline__ void epiN(const f32x4 acc[2], const float b[4],
                                     u16* dst, int lane, int wid) {
    const int c0 = wid*16 + ((lane>>4)<<2);
    const int rl = lane & 15;
#pragma unroll
    for (int tr = 0; tr < 2; ++tr) {
        int r = tr*16 + rl;
        uint2 pk = { pack2(acc[tr][0]+b[0], acc[tr][1]+b[1]),
                     pack2(acc[tr][2]+b[2], acc[tr][3]+b[3]) };
        *reinterpret_cast<uint2*>(dst + r*HD + SWZ(r, c0)) = pk;
    }
}
__device__ __forceinline__ void epiF(const f32x4 acc[2], const float* __restrict__ bias,
                                     float* dst, int lane, int wid) {
    const int c0 = wid*16 + ((lane>>4)<<2);
    const int rl = lane & 15;
    float4 b4 = *reinterpret_cast<const float4*>(bias + c0);
#pragma unroll
    for (int tr = 0; tr < 2; ++tr) {
        int r = tr*16 + rl;
        float4 v = { acc[tr][0]+b4.x, acc[tr][1]+b4.y, acc[tr][2]+b4.z, acc[tr][3]+b4.w };
        *reinterpret_cast<float4*>(dst + r*HD + c0) = v;
    }
}

// ---- prologue GEMM over Xc (lda=256) ----
__device__ __forceinline__ void gemmX(const u16* __restrict__ Xc, int kBase,
                                      const u16* __restrict__ img,
                                      int lane, int wid, f32x4 acc[2], bool init) {
    bf16x8 W[4]; loadW(img, lane, wid, W);
    const int rl = lane & 15, kq = lane >> 4;
#pragma unroll
    for (int tr = 0; tr < 2; ++tr) {
        const int r = tr*16 + rl;
        const u16* arow = Xc + r*256;
        f32x4 a = init ? f32x4{0.f,0.f,0.f,0.f} : acc[tr];
#pragma unroll
        for (int kk = 0; kk < 4; ++kk) {
            bf16x8 bf = *reinterpret_cast<const bf16x8*>(arow + SWZ(r, kBase + kk*32 + kq*8));
            a = MFMA(W[kk], bf, a);
        }
        acc[tr] = a;
    }
}

// ---- LN + relu + 2-wide head; 8 lanes/row; direct global store ----
__device__ __forceinline__ void head_ln(const u16* __restrict__ src,
                                        const float4* __restrict__ pp4,
                                        float b20, float b21, int elu, int off, int idx,
                                        float* __restrict__ dstStep)
{
    int row = idx >> 3, sub = idx & 7;
    int c0 = sub * 16;
    uint4 p0 = *reinterpret_cast<const uint4*>(src + row*HD + SWZ(row, c0));
    uint4 p1 = *reinterpret_cast<const uint4*>(src + row*HD + SWZ(row, c0+8));
    float v[16];
    v[0]=bf2f(p0.x); v[1]=bf2f(p0.x>>16); v[2]=bf2f(p0.y); v[3]=bf2f(p0.y>>16);
    v[4]=bf2f(p0.z); v[5]=bf2f(p0.z>>16); v[6]=bf2f(p0.w); v[7]=bf2f(p0.w>>16);
    v[8]=bf2f(p1.x); v[9]=bf2f(p1.x>>16); v[10]=bf2f(p1.y); v[11]=bf2f(p1.y>>16);
    v[12]=bf2f(p1.z); v[13]=bf2f(p1.z>>16); v[14]=bf2f(p1.w); v[15]=bf2f(p1.w>>16);
    float s = 0.f, sq = 0.f;
#pragma unroll
    for (int i = 0; i < 16; ++i){ s += v[i]; sq += v[i]*v[i]; }
    s += __shfl_xor(s,1); sq += __shfl_xor(sq,1);
    s += __shfl_xor(s,2); sq += __shfl_xor(sq,2);
    s += __shfl_xor(s,4); sq += __shfl_xor(sq,4);
    float mu = s * (1.f/128.f);
    float rstd = rsqrtf(sq*(1.f/128.f) - mu*mu + LN_EPS);
    float a0 = 0.f, a1 = 0.f;
#pragma unroll
    for (int i = 0; i < 16; ++i){
        float4 p = pp4[(c0 + i) ^ sub];
        float h = (v[i]-mu)*rstd*p.x + p.y;
        h = fmaxf(h, 0.f);
        a0 += h * p.z; a1 += h * p.w;
    }
    a0 += __shfl_xor(a0,1); a1 += __shfl_xor(a1,1);
    a0 += __shfl_xor(a0,2); a1 += __shfl_xor(a1,2);
    a0 += __shfl_xor(a0,4); a1 += __shfl_xor(a1,4);
    if (sub == 0){
        a0 += b20; a1 += b21;
        if (elu){
            a0 = (a0 > 0.f ? a0 : __expf(a0)-1.f) + 1.001f;
            a1 = (a1 > 0.f ? a1 : __expf(a1)-1.f) + 1.001f;
        }
        *reinterpret_cast<float2*>(dstStep + row*4 + off) = make_float2(a0, a1);
    }
}

// ---------- weight image prep: f32 -> bf16, transposed, swizzled ----------
__global__ void prep_w(const float* __restrict__ fw1, const float* __restrict__ fw2,
                       const float* __restrict__ fw3, const float* __restrict__ gw1,
                       const float* __restrict__ gw2, const float* __restrict__ dw1,
                       const float* __restrict__ sw1, const float* __restrict__ aw,
                       const float* __restrict__ pw1, u16* __restrict__ ws)
{
    int img = blockIdx.y;
    int idx = blockIdx.x * 256 + threadIdx.x;
    int k = idx >> 7, j = idx & 127;
    const float* W = fw1; int sr = k;
    switch (img) {
        case 0: W = fw1; break;  case 1: W = fw2; break;  case 2: W = fw3; break;
        case 3: W = gw1; break;  case 4: W = gw2; break;
        case 5: W = dw1; break;  case 6: W = sw1; break;
        case 7: W = aw;  break;  case 8: W = aw;  sr = k + 128; break;
        case 9: W = pw1; break;  case 10: W = pw1; sr = k + 128; break;
    }
    ws[(size_t)img*16384 + j*128 + SWZ(j, k)] = f2bf(W[(size_t)sr*128 + j]);
}

// ---------- final output reorder: ws [blk][tt][row][4] -> loc_out [gr][tt][4] ----------
__global__ void reorder_out(const float* __restrict__ wsOut, float* __restrict__ outp)
{
    __shared__ float tile[3840];
    int b = blockIdx.x;
    const float* src = wsOut + (size_t)b*3840;
#pragma unroll
    for (int j = 0; j < 15; ++j) {
        int idx = j*256 + threadIdx.x;
        int tt = idx >> 7, rc = idx & 127;
        int row = rc >> 2, c = idx & 3;
        tile[row*120 + tt*4 + c] = src[idx];
    }
    __syncthreads();
    float* dst = outp + (size_t)b*3840;
#pragma unroll
    for (int j = 0; j < 15; ++j) {
        int idx = j*256 + threadIdx.x;
        dst[idx] = tile[idx];
    }
}

// ---------- the fused persistent kernel ----------
__global__ __launch_bounds__(512, 6) void sde_fused(
    const float* __restrict__ lE, const float* __restrict__ gE,
    const float* __restrict__ noise,
    const float* __restrict__ aggr_b, const float* __restrict__ aggr_g, const float* __restrict__ aggr_be,
    const float* __restrict__ fw1, const float* __restrict__ fb1,
    const float* __restrict__ fb2, const float* __restrict__ fb3,
    const float* __restrict__ gw1, const float* __restrict__ gb1,
    const float* __restrict__ gb2, const float* __restrict__ gw3, const float* __restrict__ gb3,
    const float* __restrict__ db1, const float* __restrict__ dg, const float* __restrict__ dbe,
    const float* __restrict__ dw2, const float* __restrict__ db2,
    const float* __restrict__ sb1, const float* __restrict__ sg, const float* __restrict__ sbe,
    const float* __restrict__ sw2, const float* __restrict__ sb2,
    const float* __restrict__ pb1, const float* __restrict__ pg, const float* __restrict__ pbe,
    const float* __restrict__ pw2, const float* __restrict__ pb2,
    const unsigned char* __restrict__ pmask,
    const u16* __restrict__ wimg,
    float* __restrict__ wsOut,
    float* __restrict__ outp)
{
    // LDS (54272 B -> 3 blocks/CU):
    //   Sb@0 Ab@8K Bb@16K Cb@24K Db@32K Eb@40K (8K each)
    //   gpart[32][8] @48K (1K) | ppd @49K+1K (2K) | pps (2K)
    //   prologue aliases: Xc (16K) over Db+Eb; preLN f32 (16K) over Ab+Bb
    __shared__ __align__(16) unsigned char SMEM[54272];
    u16*  Sb    = (u16*)SMEM;
    u16*  Ab    = (u16*)(SMEM + 8192);
    u16*  Bb    = (u16*)(SMEM + 16384);
    u16*  Cb    = (u16*)(SMEM + 24576);
    u16*  Db    = (u16*)(SMEM + 32768);
    u16*  Eb    = (u16*)(SMEM + 40960);
    float* gpart = (float*)(SMEM + 49152);     // [32][8]
    float4* ppd = (float4*)(SMEM + 50176);
    float4* pps = (float4*)(SMEM + 52224);
    u16*  Xc    = (u16*)(SMEM + 32768);
    float* preLN = (float*)(SMEM + 8192);

    const int tid  = threadIdx.x;
    const int lane = tid & 63;
    const int wid  = tid >> 6;
    const int bid  = blockIdx.x;
    const int r0   = bid * RBLK;
    const int c0e  = wid*16 + ((lane>>4)<<2);

    // -------- stage params + Xc --------
    if (tid < 128) {
        int cs = tid ^ ((tid >> 4) & 7);
        ppd[cs] = make_float4(dg[tid], dbe[tid], dw2[2*tid], dw2[2*tid+1]);
        pps[cs] = make_float4(sg[tid], sbe[tid], sw2[2*tid], sw2[2*tid+1]);
    }
#pragma unroll
    for (int i = 0; i < 2; ++i) {
        int gidx = i*512 + tid;
        int r = gidx >> 5;
        int k = (gidx & 31) * 8;
        int gr = r0 + r;
        const float* src = (k < HD) ? (gE + (size_t)gr*HD + k)
                                    : (lE + (size_t)(gr & (Adim-1))*HD + (k - HD));
        float4 v0 = reinterpret_cast<const float4*>(src)[0];
        float4 v1 = reinterpret_cast<const float4*>(src)[1];
        uint4 pk = { pack2(v0.x, v0.y), pack2(v0.z, v0.w),
                     pack2(v1.x, v1.y), pack2(v1.z, v1.w) };
        *reinterpret_cast<uint4*>(Xc + r*256 + SWZ(r, k)) = pk;
    }
    __syncthreads();

    f32x4 acc[2];

    // -------- pi head --------
    gemmX(Xc, 0,   wimg + 10*16384, lane, wid, acc, true);
    gemmX(Xc, 128, wimg + 9*16384,  lane, wid, acc, false);
    epiF(acc, pb1, preLN, lane, wid);
    __syncthreads();
    {
        int row = tid >> 4, sub = tid & 15;
        int c0 = sub * 8;
        const float* yr = preLN + row*HD + c0;
        float v[8]; float s = 0.f, sq = 0.f;
#pragma unroll
        for (int i = 0; i < 8; ++i){ float x = yr[i]; v[i] = x; s += x; sq += x*x; }
        s += __shfl_xor(s,1); sq += __shfl_xor(sq,1);
        s += __shfl_xor(s,2); sq += __shfl_xor(sq,2);
        s += __shfl_xor(s,4); sq += __shfl_xor(sq,4);
        s += __shfl_xor(s,8); sq += __shfl_xor(sq,8);
        float mu = s*(1.f/128.f);
        float rstd = rsqrtf(sq*(1.f/128.f) - mu*mu + LN_EPS);
        float a0 = 0.f;
#pragma unroll
        for (int i = 0; i < 8; ++i){
            int cc = c0 + i;
            float h = (v[i]-mu)*rstd*pg[cc] + pbe[cc];
            a0 += fmaxf(h, 0.f) * pw2[cc];
        }
        a0 += __shfl_xor(a0,1); a0 += __shfl_xor(a0,2);
        a0 += __shfl_xor(a0,4); a0 += __shfl_xor(a0,8);
        if (sub == 0) {
            int gr = r0 + row;
            outp[PI_OFF + (size_t)(gr & (Adim-1))*6 + (gr >> 12)] = a0 + pb2[0];
        }
    }
    if (tid < RBLK) {
        int gr = r0 + tid;
        if (gr < Adim) {
            const unsigned char* pm = pmask + (size_t)gr*50 + 20;
            float* o = outp + MASK_OFF + (size_t)gr*TSTEPS;
#pragma unroll
            for (int i = 0; i < TSTEPS; ++i) o[i] = pm[i] ? 0.f : 1.f;
        }
    }
    __syncthreads();

    // -------- aggr head -> h0 --------
    gemmX(Xc, 0,   wimg + 7*16384, lane, wid, acc, true);
    gemmX(Xc, 128, wimg + 8*16384, lane, wid, acc, false);
    __syncthreads();
    epiF(acc, aggr_b, preLN, lane, wid);
    __syncthreads();

    float y0,y1,y2,y3,y4,y5,y6,y7;
    {
        int row = tid >> 4, sub = tid & 15;
        int c0 = sub * 8;
        const float* yr = preLN + row*HD + c0;
        float v[8]; float s = 0.f, sq = 0.f;
#pragma unroll
        for (int i = 0; i < 8; ++i){ float x = yr[i]; v[i] = x; s += x; sq += x*x; }
        s += __shfl_xor(s,1); sq += __shfl_xor(sq,1);
        s += __shfl_xor(s,2); sq += __shfl_xor(sq,2);
        s += __shfl_xor(s,4); sq += __shfl_xor(sq,4);
        s += __shfl_xor(s,8); sq += __shfl_xor(sq,8);
        float mu = s*(1.f/128.f);
        float rstd = rsqrtf(sq*(1.f/128.f) - mu*mu + LN_EPS);
#pragma unroll
        for (int i = 0; i < 8; ++i){
            int cc = c0 + i;
            float h = (v[i]-mu)*rstd*aggr_g[cc] + aggr_be[cc];
            v[i] = fmaxf(h, 0.f);
        }
        y0=v[0]; y1=v[1]; y2=v[2]; y3=v[3]; y4=v[4]; y5=v[5]; y6=v[6]; y7=v[7];
        uint4 pk = { pack2(v[0],v[1]), pack2(v[2],v[3]),
                     pack2(v[4],v[5]), pack2(v[6],v[7]) };
        *reinterpret_cast<uint4*>(&Sb[row*HD + SWZ(row, c0)]) = pk;
    }

    const float db20 = db2[0], db21 = db2[1];
    const float sb20 = sb2[0], sb21 = sb2[1];
    const float gb3v = gb3[0];

    f32x4 nz0, nz1;
    float grow = 0.f;
    float* wsB = wsOut + (size_t)bid*TSTEPS*128;
    __syncthreads();

    // -------- PhA(-1): L1f,L1g at t=0 --------
    {
        float4 a0 = *(const float4*)(fb1 + c0e);
        float4 a2 = *(const float4*)(fw1 + 129*HD + c0e);
        float4 a3 = *(const float4*)(gb1 + c0e);
        float4 a5 = *(const float4*)(gw1 + 129*HD + c0e);
        float bF[4] = { a0.x+a2.x, a0.y+a2.y, a0.z+a2.z, a0.w+a2.w };
        float bG[4] = { a3.x+a5.x, a3.y+a5.y, a3.z+a5.z, a3.w+a5.w };
        bf16x8 W1[4], W2[4];
        loadW(wimg + 0*16384, lane, wid, W1);
        loadW(wimg + 3*16384, lane, wid, W2);
        f32x4 aF[2], aG[2];
        gemm2(Sb, W1, W2, lane, aF, aG);
        epiT(aF, bF, Ab, lane, wid);
        epiT(aG, bG, Bb, lane, wid);
    }
    __syncthreads();

    // -------- Euler-Maruyama scan: 4 barriers/step --------
    for (int k = 0; k < TSTEPS; ++k) {
        // PhB: L2f(Ab->Cb); L2g(Bb->gpart fused GEMV); heads(k-1)
        {
            float4 b6 = *(const float4*)(fb2 + c0e);
            float bb[4] = { b6.x, b6.y, b6.z, b6.w };
            bf16x8 Wf[4];
            loadW(wimg + 1*16384, lane, wid, Wf);
            f32x4 a1[2];
            gemm1(Ab, Wf, lane, a1);
            epiT(a1, bb, Cb, lane, wid);
            float4 b7 = *(const float4*)(gb2 + c0e);
            float4 g3 = *(const float4*)(gw3 + c0e);
            loadW(wimg + 4*16384, lane, wid, Wf);
            gemm1(Bb, Wf, lane, a1);
            float p0 = tanh_f(a1[0][0]+b7.x)*g3.x + tanh_f(a1[0][1]+b7.y)*g3.y
                     + tanh_f(a1[0][2]+b7.z)*g3.z + tanh_f(a1[0][3]+b7.w)*g3.w;
            float p1 = tanh_f(a1[1][0]+b7.x)*g3.x + tanh_f(a1[1][1]+b7.y)*g3.y
                     + tanh_f(a1[1][2]+b7.z)*g3.z + tanh_f(a1[1][3]+b7.w)*g3.w;
            p0 += __shfl_xor(p0, 16); p0 += __shfl_xor(p0, 32);
            p1 += __shfl_xor(p1, 16); p1 += __shfl_xor(p1, 32);
            if ((lane >> 4) == 0) {
                int rl2 = lane & 15;
                gpart[rl2*8 + wid]      = p0;
                gpart[(16+rl2)*8 + wid] = p1;
            }
        }
        if (k >= 1) {
            float* dstStep = wsB + (size_t)(k-1)*128;
            if (tid < 256) head_ln(Db, ppd, db20, db21, 0, 0, tid, dstStep);
            else           head_ln(Eb, pps, sb20, sb21, 1, 2, tid-256, dstStep);
        }
        __syncthreads();
        // PhC: noise nt-prefetch; L3f drift (Cb->Db); gpart reduce -> grow
        {
            const float* np = noise + ((size_t)k*NROWS + r0)*HD + (size_t)tid*8;
            nz0 = __builtin_nontemporal_load(reinterpret_cast<const f32x4*>(np));
            nz1 = __builtin_nontemporal_load(reinterpret_cast<const f32x4*>(np + 4));
        }
        {
            float4 b8 = *(const float4*)(fb3 + c0e);
            float bb[4] = { b8.x, b8.y, b8.z, b8.w };
            bf16x8 Wf[4];
            loadW(wimg + 2*16384, lane, wid, Wf);
            f32x4 a1[2];
            gemm1(Cb, Wf, lane, a1);
            epiN(a1, bb, Db, lane, wid);
        }
        {
            int row = tid >> 4;
            const float* gp = gpart + row*8;
            float s = gp[0]+gp[1]+gp[2]+gp[3]+gp[4]+gp[5]+gp[6]+gp[7];
            grow = sigm_f(s + gb3v) * SQDT_C;
        }
        __syncthreads();
        // PhD: Euler update (state regs) -> Sb
        {
            int row = tid >> 4, sub = tid & 15;
            int sk = SWZ(row, sub*8);
            uint4 dpk = *reinterpret_cast<const uint4*>(Db + row*HD + sk);
            y0 += bf2f(dpk.x)     * DT_C + grow*nz0[0];
            y1 += bf2f(dpk.x>>16) * DT_C + grow*nz0[1];
            y2 += bf2f(dpk.y)     * DT_C + grow*nz0[2];
            y3 += bf2f(dpk.y>>16) * DT_C + grow*nz0[3];
            y4 += bf2f(dpk.z)     * DT_C + grow*nz1[0];
            y5 += bf2f(dpk.z>>16) * DT_C + grow*nz1[1];
            y6 += bf2f(dpk.w)     * DT_C + grow*nz1[2];
            y7 += bf2f(dpk.w>>16) * DT_C + grow*nz1[3];
            uint4 s4 = { pack2(y0,y1), pack2(y2,y3), pack2(y4,y5), pack2(y6,y7) };
            *reinterpret_cast<uint4*>(Sb + row*HD + sk) = s4;
        }
        __syncthreads();
        // PhA(k): L1f,L1g(t_{k+1}) if any; D1,S1 on new state -> Db,Eb
        if (k < TSTEPS-1) {
            float t = (k+1) * DT_C;
            float st = __sinf(t), ct = __cosf(t);
            float4 a0 = *(const float4*)(fb1 + c0e);
            float4 a1 = *(const float4*)(fw1 + 128*HD + c0e);
            float4 a2 = *(const float4*)(fw1 + 129*HD + c0e);
            float4 a3 = *(const float4*)(gb1 + c0e);
            float4 a4 = *(const float4*)(gw1 + 128*HD + c0e);
            float4 a5 = *(const float4*)(gw1 + 129*HD + c0e);
            float bF[4] = { a0.x + st*a1.x + ct*a2.x, a0.y + st*a1.y + ct*a2.y,
                            a0.z + st*a1.z + ct*a2.z, a0.w + st*a1.w + ct*a2.w };
            float bG[4] = { a3.x + st*a4.x + ct*a5.x, a3.y + st*a4.y + ct*a5.y,
                            a3.z + st*a4.z + ct*a5.z, a3.w + st*a4.w + ct*a5.w };
            bf16x8 W1[4], W2[4];
            loadW(wimg + 0*16384, lane, wid, W1);
            loadW(wimg + 3*16384, lane, wid, W2);
            f32x4 aF[2], aG[2];
            gemm2(Sb, W1, W2, lane, aF, aG);
            epiT(aF, bF, Ab, lane, wid);
            epiT(aG, bG, Bb, lane, wid);
        }
        {
            float4 a9 = *(const float4*)(db1 + c0e);
            float4 aa = *(const float4*)(sb1 + c0e);
            float bD[4] = { a9.x, a9.y, a9.z, a9.w };
            float bS[4] = { aa.x, aa.y, aa.z, aa.w };
            bf16x8 W1[4], W2[4];
            loadW(wimg + 5*16384, lane, wid, W1);
            loadW(wimg + 6*16384, lane, wid, W2);
            f32x4 aD[2], aS2[2];
            gemm2(Sb, W1, W2, lane, aD, aS2);
            epiN(aD, bD, Db, lane, wid);
            epiN(aS2, bS, Eb, lane, wid);
        }
        __syncthreads();
    }
    // final heads (output TSTEPS-1)
    {
        float* dstStep = wsB + (size_t)(TSTEPS-1)*128;
        if (tid < 256) head_ln(Db, ppd, db20, db21, 0, 0, tid, dstStep);
        else           head_ln(Eb, pps, sb20, sb21, 1, 2, tid-256, dstStep);
    }
}

extern "C" void kernel_launch(void* const* d_in, const int* in_sizes, int n_in,
                              void* d_out, int out_size, void* d_ws, size_t ws_size,
                              hipStream_t stream) {
    const float* lE      = (const float*)d_in[0];
    const float* gE      = (const float*)d_in[1];
    const float* noise   = (const float*)d_in[2];
    const float* aggr_w  = (const float*)d_in[3];
    const float* aggr_b  = (const float*)d_in[4];
    const float* aggr_g  = (const float*)d_in[5];
    const float* aggr_be = (const float*)d_in[6];
    const float* fw1 = (const float*)d_in[7];
    const float* fb1 = (const float*)d_in[8];
    const float* fw2 = (const float*)d_in[9];
    const float* fb2 = (const float*)d_in[10];
    const float* fw3 = (const float*)d_in[11];
    const float* fb3 = (const float*)d_in[12];
    const float* gw1 = (const float*)d_in[13];
    const float* gb1 = (const float*)d_in[14];
    const float* gw2 = (const float*)d_in[15];
    const float* gb2 = (const float*)d_in[16];
    const float* gw3 = (const float*)d_in[17];
    const float* gb3 = (const float*)d_in[18];
    const float* dw1 = (const float*)d_in[19];
    const float* db1 = (const float*)d_in[20];
    const float* dg  = (const float*)d_in[21];
    const float* dbe = (const float*)d_in[22];
    const float* dw2 = (const float*)d_in[23];
    const float* db2 = (const float*)d_in[24];
    const float* sw1 = (const float*)d_in[25];
    const float* sb1 = (const float*)d_in[26];
    const float* sg  = (const float*)d_in[27];
    const float* sbe = (const float*)d_in[28];
    const float* sw2 = (const float*)d_in[29];
    const float* sb2 = (const float*)d_in[30];
    const float* pw1 = (const float*)d_in[31];
    const float* pb1 = (const float*)d_in[32];
    const float* pg  = (const float*)d_in[33];
    const float* pbe = (const float*)d_in[34];
    const float* pw2 = (const float*)d_in[35];
    const float* pb2 = (const float*)d_in[36];
    const unsigned char* pmask = (const unsigned char*)d_in[37];
    float* outp = (float*)d_out;
    u16* wimg = (u16*)d_ws;                                  // 352 KB
    float* wsOut = (float*)((char*)d_ws + 360448);           // 768*3840 floats = 11.8 MB

    prep_w<<<dim3(64, 11), 256, 0, stream>>>(fw1, fw2, fw3, gw1, gw2, dw1, sw1,
                                             aggr_w, pw1, wimg);
    sde_fused<<<NBLKS, 512, 0, stream>>>(
        lE, gE, noise, aggr_b, aggr_g, aggr_be,
        fw1, fb1, fb2, fb3,
        gw1, gb1, gb2, gw3, gb3,
        db1, dg, dbe, dw2, db2,
        sb1, sg, sbe, sw2, sb2,
        pb1, pg, pbe, pw2, pb2,
        pmask, wimg, wsOut, outp);
    reorder_out<<<NBLKS, 256, 0, stream>>>(wsOut, outp);
}

// Round 9
// 1395.434 us; speedup vs baseline: 1.0134x; 1.0134x over previous
//
#include <hip/hip_runtime.h>

#define Adim 4096
#define HD 128
#define TSTEPS 30
#define NROWS 24576
#define RBLK 96
#define NBLKS 256           // exactly 1 block/CU, single round
#define DT_C 0.2f
#define SQDT_C 0.44721359549995794f
#define LN_EPS 1e-5f

#define PI_OFF   2949120    // 6*4096*30*4
#define MASK_OFF 2973696    // PI_OFF + 24576

typedef unsigned short u16;
typedef __bf16 bf16x8 __attribute__((ext_vector_type(8)));
typedef float f32x4 __attribute__((ext_vector_type(4)));

__device__ __forceinline__ u16 f2bf(float x){
    unsigned u = __builtin_bit_cast(unsigned, x);
    u = (u + 0x7fffu + ((u >> 16) & 1u)) >> 16;
    return (u16)u;
}
__device__ __forceinline__ float bf2f(unsigned h){
    unsigned u = (h & 0xffffu) << 16;
    return __builtin_bit_cast(float, u);
}
__device__ __forceinline__ unsigned pack2(float a, float b){
    unsigned r;
    asm("v_cvt_pk_bf16_f32 %0, %1, %2" : "=v"(r) : "v"(a), "v"(b));
    return r;
}
__device__ __forceinline__ float tanh_f(float x){
    return 1.0f - 2.0f / (1.0f + __expf(2.0f * x));
}
__device__ __forceinline__ float sigm_f(float x){
    return 1.0f / (1.0f + __expf(-x));
}
#define SWZ(r,k) ((k) ^ (((r)&7)<<3))
#define MFMA(A,B,C) __builtin_amdgcn_mfma_f32_16x16x32_bf16(A, B, C, 0, 0, 0)

// ---- per-wave weight fragments: 16 output channels per wave ----
__device__ __forceinline__ void loadW(const u16* __restrict__ img, int lane, int wid,
                                      bf16x8 W[4]) {
    const int c = wid*16 + (lane & 15);
    const int kq = lane >> 4;
#pragma unroll
    for (int kk = 0; kk < 4; ++kk)
        W[kk] = *reinterpret_cast<const bf16x8*>(img + c*HD + SWZ(c, kk*32 + kq*8));
}

// ---- per-tile epilogues (lane: rows r, 4 consecutive channels c0) ----
__device__ __forceinline__ void epiT1(const f32x4& a, const float b[4],
                                      u16* dst, int r, int c0) {
    uint2 pk = { pack2(tanh_f(a[0]+b[0]), tanh_f(a[1]+b[1])),
                 pack2(tanh_f(a[2]+b[2]), tanh_f(a[3]+b[3])) };
    *reinterpret_cast<uint2*>(dst + r*HD + SWZ(r, c0)) = pk;
}
__device__ __forceinline__ void epiN1(const f32x4& a, const float b[4],
                                      u16* dst, int r, int c0) {
    uint2 pk = { pack2(a[0]+b[0], a[1]+b[1]), pack2(a[2]+b[2], a[3]+b[3]) };
    *reinterpret_cast<uint2*>(dst + r*HD + SWZ(r, c0)) = pk;
}

// ---- prologue GEMM over Xc (lda=256), 6 row tiles ----
__device__ __forceinline__ void gemmX6(const u16* __restrict__ Xc, int kBase,
                                       const u16* __restrict__ img,
                                       int lane, int wid, f32x4 acc[6], bool init) {
    bf16x8 W[4]; loadW(img, lane, wid, W);
    const int rl = lane & 15, kq = lane >> 4;
#pragma unroll
    for (int tr = 0; tr < 6; ++tr) {
        const int r = tr*16 + rl;
        const u16* arow = Xc + r*256;
        f32x4 a = init ? f32x4{0.f,0.f,0.f,0.f} : acc[tr];
#pragma unroll
        for (int kk = 0; kk < 4; ++kk) {
            bf16x8 bf = *reinterpret_cast<const bf16x8*>(arow + SWZ(r, kBase + kk*32 + kq*8));
            a = MFMA(W[kk], bf, a);
        }
        acc[tr] = a;
    }
}
__device__ __forceinline__ void epiF6(const f32x4 acc[6], const float* __restrict__ bias,
                                      float* dst, int lane, int wid) {
    const int c0 = wid*16 + ((lane>>4)<<2);
    const int rl = lane & 15;
    float4 b4 = *reinterpret_cast<const float4*>(bias + c0);
#pragma unroll
    for (int tr = 0; tr < 6; ++tr) {
        int r = tr*16 + rl;
        float4 v = { acc[tr][0]+b4.x, acc[tr][1]+b4.y, acc[tr][2]+b4.z, acc[tr][3]+b4.w };
        *reinterpret_cast<float4*>(dst + r*HD + c0) = v;
    }
}

// ---- LN + relu + 2-wide head; 4 lanes/row, 32 ch/lane, two-pass (reg-light) ----
__device__ __forceinline__ void head_ln4g(const u16* __restrict__ src,
                                          const float4* __restrict__ pp4,
                                          float b20, float b21, int elu, int off,
                                          int idx, float* __restrict__ dstRow)
{
    int row = idx >> 2, part = idx & 3;
    int c0 = part * 32;
    uint4 p[4];
#pragma unroll
    for (int u = 0; u < 4; ++u)
        p[u] = *reinterpret_cast<const uint4*>(src + row*HD + SWZ(row, c0 + u*8));
    float s = 0.f, sq = 0.f;
#pragma unroll
    for (int u = 0; u < 4; ++u) {
        float a0=bf2f(p[u].x), a1=bf2f(p[u].x>>16), a2=bf2f(p[u].y), a3=bf2f(p[u].y>>16);
        float a4=bf2f(p[u].z), a5=bf2f(p[u].z>>16), a6=bf2f(p[u].w), a7=bf2f(p[u].w>>16);
        s  += a0+a1+a2+a3+a4+a5+a6+a7;
        sq += a0*a0+a1*a1+a2*a2+a3*a3+a4*a4+a5*a5+a6*a6+a7*a7;
    }
    s += __shfl_xor(s,1); sq += __shfl_xor(sq,1);
    s += __shfl_xor(s,2); sq += __shfl_xor(sq,2);
    float mu = s * (1.f/128.f);
    float rstd = rsqrtf(sq*(1.f/128.f) - mu*mu + LN_EPS);
    float a0acc = 0.f, a1acc = 0.f;
#pragma unroll
    for (int u = 0; u < 4; ++u) {
        float vv[8] = { bf2f(p[u].x), bf2f(p[u].x>>16), bf2f(p[u].y), bf2f(p[u].y>>16),
                        bf2f(p[u].z), bf2f(p[u].z>>16), bf2f(p[u].w), bf2f(p[u].w>>16) };
#pragma unroll
        for (int i = 0; i < 8; ++i) {
            int c = c0 + u*8 + i;
            float4 pr = pp4[c ^ ((c>>4)&7)];
            float h = (vv[i]-mu)*rstd*pr.x + pr.y;
            h = fmaxf(h, 0.f);
            a0acc += h*pr.z; a1acc += h*pr.w;
        }
    }
    a0acc += __shfl_xor(a0acc,1); a1acc += __shfl_xor(a1acc,1);
    a0acc += __shfl_xor(a0acc,2); a1acc += __shfl_xor(a1acc,2);
    if (part == 0) {
        a0acc += b20; a1acc += b21;
        if (elu) {
            a0acc = (a0acc > 0.f ? a0acc : __expf(a0acc)-1.f) + 1.001f;
            a1acc = (a1acc > 0.f ? a1acc : __expf(a1acc)-1.f) + 1.001f;
        }
        *reinterpret_cast<float2*>(dstRow + row*4 + off) = make_float2(a0acc, a1acc);
    }
}

// ---------- weight image prep: f32 -> bf16, transposed, swizzled ----------
__global__ void prep_w(const float* __restrict__ fw1, const float* __restrict__ fw2,
                       const float* __restrict__ fw3, const float* __restrict__ gw1,
                       const float* __restrict__ gw2, const float* __restrict__ dw1,
                       const float* __restrict__ sw1, const float* __restrict__ aw,
                       const float* __restrict__ pw1, u16* __restrict__ ws)
{
    int img = blockIdx.y;
    int idx = blockIdx.x * 256 + threadIdx.x;
    int k = idx >> 7, j = idx & 127;
    const float* W = fw1; int sr = k;
    switch (img) {
        case 0: W = fw1; break;  case 1: W = fw2; break;  case 2: W = fw3; break;
        case 3: W = gw1; break;  case 4: W = gw2; break;
        case 5: W = dw1; break;  case 6: W = sw1; break;
        case 7: W = aw;  break;  case 8: W = aw;  sr = k + 128; break;
        case 9: W = pw1; break;  case 10: W = pw1; sr = k + 128; break;
    }
    ws[(size_t)img*16384 + j*128 + SWZ(j, k)] = f2bf(W[(size_t)sr*128 + j]);
}

// ---------- final output reorder: ws [blk][tt][row][4] -> loc_out [gr][tt][4] ----------
__global__ void reorder_out(const float* __restrict__ wsOut, float* __restrict__ outp)
{
    __shared__ float tile[11520];
    int b = blockIdx.x;
    int tid = threadIdx.x;                    // 384
    const float* src = wsOut + (size_t)b*11520;
    int row = tid >> 2, c = tid & 3;
#pragma unroll
    for (int j = 0; j < TSTEPS; ++j)
        tile[row*120 + j*4 + c] = src[j*384 + tid];
    __syncthreads();
    float* dst = outp + (size_t)b*11520;
#pragma unroll
    for (int j = 0; j < TSTEPS; ++j)
        dst[j*384 + tid] = tile[j*384 + tid];
}

// ---------- the fused persistent kernel ----------
__global__ __launch_bounds__(512, 2) void sde_fused(
    const float* __restrict__ lE, const float* __restrict__ gE,
    const float* __restrict__ noise,
    const float* __restrict__ aggr_b, const float* __restrict__ aggr_g, const float* __restrict__ aggr_be,
    const float* __restrict__ fw1, const float* __restrict__ fb1,
    const float* __restrict__ fb2, const float* __restrict__ fb3,
    const float* __restrict__ gw1, const float* __restrict__ gb1,
    const float* __restrict__ gb2, const float* __restrict__ gw3, const float* __restrict__ gb3,
    const float* __restrict__ db1, const float* __restrict__ dg, const float* __restrict__ dbe,
    const float* __restrict__ dw2, const float* __restrict__ db2,
    const float* __restrict__ sb1, const float* __restrict__ sg, const float* __restrict__ sbe,
    const float* __restrict__ sw2, const float* __restrict__ sb2,
    const float* __restrict__ pb1, const float* __restrict__ pg, const float* __restrict__ pbe,
    const float* __restrict__ pw2, const float* __restrict__ pb2,
    const unsigned char* __restrict__ pmask,
    const u16* __restrict__ wimg,
    float* __restrict__ wsOut,
    float* __restrict__ outp)
{
    // LDS: P0@0 P1@24K Bb@48K Db@72K Eb@96K (24K each, 96x128 bf16)
    //      gpart[96][12] f32 @120K (4.6K) | ppd @124.5K (2K) | pps (2K)  -> 131.6K
    // prologue aliases: Xc (48K) over P0+P1; preLN f32 (48K) over Bb+Db
    __shared__ __align__(16) unsigned char SMEM[133632];
    u16* P0 = (u16*)SMEM;
    u16* P1 = (u16*)(SMEM + 24576);
    u16* Bb = (u16*)(SMEM + 49152);
    u16* Db = (u16*)(SMEM + 73728);
    u16* Eb = (u16*)(SMEM + 98304);
    float* gpart = (float*)(SMEM + 122880);    // [96][12]
    float4* ppd = (float4*)(SMEM + 127488);
    float4* pps = (float4*)(SMEM + 129536);
    u16* Xc = (u16*)SMEM;
    float* preLN = (float*)(SMEM + 49152);

    const int tid  = threadIdx.x;
    const int lane = tid & 63;
    const int wid  = tid >> 6;
    const int bid  = blockIdx.x;
    const int r0   = bid * RBLK;
    const int rl   = lane & 15;
    const int kq   = lane >> 4;
    const int c0e  = wid*16 + (kq<<2);

    // -------- stage params + Xc --------
    if (tid < 128) {
        int cs = tid ^ ((tid >> 4) & 7);
        ppd[cs] = make_float4(dg[tid], dbe[tid], dw2[2*tid], dw2[2*tid+1]);
        pps[cs] = make_float4(sg[tid], sbe[tid], sw2[2*tid], sw2[2*tid+1]);
    }
#pragma unroll
    for (int i = 0; i < 6; ++i) {
        int gidx = i*512 + tid;             // 0..3071
        int r = gidx >> 5;
        int k = (gidx & 31) * 8;
        int gr = r0 + r;
        const float* src = (k < HD) ? (gE + (size_t)gr*HD + k)
                                    : (lE + (size_t)(gr & (Adim-1))*HD + (k - HD));
        float4 v0 = reinterpret_cast<const float4*>(src)[0];
        float4 v1 = reinterpret_cast<const float4*>(src)[1];
        uint4 pk = { pack2(v0.x, v0.y), pack2(v0.z, v0.w),
                     pack2(v1.x, v1.y), pack2(v1.z, v1.w) };
        *reinterpret_cast<uint4*>(Xc + r*256 + SWZ(r, k)) = pk;
    }
    __syncthreads();

    f32x4 acc6[6];

    // -------- pi head --------
    gemmX6(Xc, 0,   wimg + 10*16384, lane, wid, acc6, true);   // ge part
    gemmX6(Xc, 128, wimg + 9*16384,  lane, wid, acc6, false);  // le part
    epiF6(acc6, pb1, preLN, lane, wid);
    __syncthreads();
    if (tid < 384) {
        int row = tid >> 2, part = tid & 3;
        int c0 = part * 32;
        const float* yr = preLN + row*HD + c0;
        float v[32]; float s = 0.f, sq = 0.f;
#pragma unroll
        for (int i = 0; i < 32; ++i){ float x = yr[i]; v[i] = x; s += x; sq += x*x; }
        s += __shfl_xor(s,1); sq += __shfl_xor(sq,1);
        s += __shfl_xor(s,2); sq += __shfl_xor(sq,2);
        float mu = s*(1.f/128.f);
        float rstd = rsqrtf(sq*(1.f/128.f) - mu*mu + LN_EPS);
        float a0 = 0.f;
#pragma unroll
        for (int i = 0; i < 32; ++i){
            int cc = c0 + i;
            float h = (v[i]-mu)*rstd*pg[cc] + pbe[cc];
            a0 += fmaxf(h, 0.f) * pw2[cc];
        }
        a0 += __shfl_xor(a0,1); a0 += __shfl_xor(a0,2);
        if (part == 0) {
            int gr = r0 + row;
            outp[PI_OFF + (size_t)(gr & (Adim-1))*6 + (gr >> 12)] = a0 + pb2[0];
        }
    }
    if (tid < RBLK) {
        int gr = r0 + tid;
        if (gr < Adim) {
            const unsigned char* pm = pmask + (size_t)gr*50 + 20;
            float* o = outp + MASK_OFF + (size_t)gr*TSTEPS;
#pragma unroll
            for (int i = 0; i < TSTEPS; ++i) o[i] = pm[i] ? 0.f : 1.f;
        }
    }
    __syncthreads();

    // -------- aggr head -> h0 --------
    gemmX6(Xc, 0,   wimg + 7*16384, lane, wid, acc6, true);
    gemmX6(Xc, 128, wimg + 8*16384, lane, wid, acc6, false);
    __syncthreads();
    epiF6(acc6, aggr_b, preLN, lane, wid);
    __syncthreads();
    if (tid < 384) {               // LN + relu -> preLN (post-LN f32, in place) + P0 (bf16)
        int row = tid >> 2, part = tid & 3;
        int c0 = part * 32;
        float* yr = preLN + row*HD + c0;
        float v[32]; float s = 0.f, sq = 0.f;
#pragma unroll
        for (int i = 0; i < 32; ++i){ float x = yr[i]; v[i] = x; s += x; sq += x*x; }
        s += __shfl_xor(s,1); sq += __shfl_xor(sq,1);
        s += __shfl_xor(s,2); sq += __shfl_xor(sq,2);
        float mu = s*(1.f/128.f);
        float rstd = rsqrtf(sq*(1.f/128.f) - mu*mu + LN_EPS);
#pragma unroll
        for (int i = 0; i < 32; ++i){
            int cc = c0 + i;
            float h = (v[i]-mu)*rstd*aggr_g[cc] + aggr_be[cc];
            v[i] = fmaxf(h, 0.f);
        }
#pragma unroll
        for (int u = 0; u < 8; ++u)
            *reinterpret_cast<float4*>(yr + u*4) = *(float4*)&v[u*4];
#pragma unroll
        for (int u = 0; u < 4; ++u) {
            uint4 pk = { pack2(v[u*8+0],v[u*8+1]), pack2(v[u*8+2],v[u*8+3]),
                         pack2(v[u*8+4],v[u*8+5]), pack2(v[u*8+6],v[u*8+7]) };
            *reinterpret_cast<uint4*>(&P0[row*HD + SWZ(row, c0 + u*8)]) = pk;
        }
    }
    __syncthreads();

    // -------- y state into registers (D-layout) --------
    f32x4 y6[6];
#pragma unroll
    for (int tr = 0; tr < 6; ++tr)
        y6[tr] = *reinterpret_cast<const f32x4*>(preLN + (tr*16+rl)*HD + c0e);
    __syncthreads();

    // -------- loop weights into registers (112 VGPR) --------
    bf16x8 WF1[4], WG1[4], WF2[4], WG2[4], WF3[4], WD1[4], WS1[4];
    loadW(wimg + 0*16384, lane, wid, WF1);
    loadW(wimg + 3*16384, lane, wid, WG1);
    loadW(wimg + 1*16384, lane, wid, WF2);
    loadW(wimg + 4*16384, lane, wid, WG2);
    loadW(wimg + 2*16384, lane, wid, WF3);
    loadW(wimg + 5*16384, lane, wid, WD1);
    loadW(wimg + 6*16384, lane, wid, WS1);

    const float db20 = db2[0], db21 = db2[1];
    const float sb20 = sb2[0], sb21 = sb2[1];
    const float gb3v = gb3[0];

    u16* Sb = P0;      // current bf16 state
    u16* Ab = P1;      // h1f slot / next state target
    f32x4 nz[6];
    float* wsB = wsOut + (size_t)bid*TSTEPS*384;

    // -------- Euler-Maruyama scan: 3 barriers/step, tile-streamed --------
    for (int k = 0; k <= TSTEPS; ++k) {
        const bool doL1 = (k < TSTEPS), doDS = (k >= 1);
        // PhA: L1f,L1g (+time bias) and D1,S1 on state Sb, shared tile reads
        {
            float bF[4], bG[4], bD[4], bS[4];
            if (doL1) {
                float t = k * DT_C;
                float st = __sinf(t), ct = __cosf(t);
                float4 a0 = *(const float4*)(fb1 + c0e);
                float4 a1 = *(const float4*)(fw1 + 128*HD + c0e);
                float4 a2 = *(const float4*)(fw1 + 129*HD + c0e);
                float4 a3 = *(const float4*)(gb1 + c0e);
                float4 a4 = *(const float4*)(gw1 + 128*HD + c0e);
                float4 a5 = *(const float4*)(gw1 + 129*HD + c0e);
                bF[0]=a0.x+st*a1.x+ct*a2.x; bF[1]=a0.y+st*a1.y+ct*a2.y;
                bF[2]=a0.z+st*a1.z+ct*a2.z; bF[3]=a0.w+st*a1.w+ct*a2.w;
                bG[0]=a3.x+st*a4.x+ct*a5.x; bG[1]=a3.y+st*a4.y+ct*a5.y;
                bG[2]=a3.z+st*a4.z+ct*a5.z; bG[3]=a3.w+st*a4.w+ct*a5.w;
            }
            if (doDS) {
                float4 a9 = *(const float4*)(db1 + c0e);
                float4 aa = *(const float4*)(sb1 + c0e);
                bD[0]=a9.x; bD[1]=a9.y; bD[2]=a9.z; bD[3]=a9.w;
                bS[0]=aa.x; bS[1]=aa.y; bS[2]=aa.z; bS[3]=aa.w;
            }
#pragma unroll
            for (int tr = 0; tr < 6; ++tr) {
                const int r = tr*16 + rl;
                const u16* arow = Sb + r*HD;
                bf16x8 x0 = *reinterpret_cast<const bf16x8*>(arow + SWZ(r, 0*32 + kq*8));
                bf16x8 x1 = *reinterpret_cast<const bf16x8*>(arow + SWZ(r, 1*32 + kq*8));
                bf16x8 x2 = *reinterpret_cast<const bf16x8*>(arow + SWZ(r, 2*32 + kq*8));
                bf16x8 x3 = *reinterpret_cast<const bf16x8*>(arow + SWZ(r, 3*32 + kq*8));
                if (doL1) {
                    f32x4 aF = {0.f,0.f,0.f,0.f}, aG = {0.f,0.f,0.f,0.f};
                    aF = MFMA(WF1[0],x0,aF); aF = MFMA(WF1[1],x1,aF);
                    aF = MFMA(WF1[2],x2,aF); aF = MFMA(WF1[3],x3,aF);
                    aG = MFMA(WG1[0],x0,aG); aG = MFMA(WG1[1],x1,aG);
                    aG = MFMA(WG1[2],x2,aG); aG = MFMA(WG1[3],x3,aG);
                    epiT1(aF, bF, Ab, r, c0e);
                    epiT1(aG, bG, Bb, r, c0e);
                }
                if (doDS) {
                    f32x4 aD = {0.f,0.f,0.f,0.f}, aS = {0.f,0.f,0.f,0.f};
                    aD = MFMA(WD1[0],x0,aD); aD = MFMA(WD1[1],x1,aD);
                    aD = MFMA(WD1[2],x2,aD); aD = MFMA(WD1[3],x3,aD);
                    aS = MFMA(WS1[0],x0,aS); aS = MFMA(WS1[1],x1,aS);
                    aS = MFMA(WS1[2],x2,aS); aS = MFMA(WS1[3],x3,aS);
                    epiN1(aD, bD, Db, r, c0e);
                    epiN1(aS, bS, Eb, r, c0e);
                }
            }
        }
        __syncthreads();
        // PhB: noise prefetch; L2f(Ab->Sb); L2g(Bb->gpart, fused gw3); head-D(k-1)
        if (doL1) {
            const float* nb = noise + ((size_t)k*NROWS + r0)*HD;
#pragma unroll
            for (int tr = 0; tr < 6; ++tr)
                nz[tr] = __builtin_nontemporal_load(
                    reinterpret_cast<const f32x4*>(nb + (size_t)(tr*16+rl)*HD + c0e));
            float4 b6 = *(const float4*)(fb2 + c0e);
            float bb2[4] = { b6.x, b6.y, b6.z, b6.w };
#pragma unroll
            for (int tr = 0; tr < 6; ++tr) {
                const int r = tr*16 + rl;
                const u16* arow = Ab + r*HD;
                bf16x8 x0 = *reinterpret_cast<const bf16x8*>(arow + SWZ(r, 0*32 + kq*8));
                bf16x8 x1 = *reinterpret_cast<const bf16x8*>(arow + SWZ(r, 1*32 + kq*8));
                bf16x8 x2 = *reinterpret_cast<const bf16x8*>(arow + SWZ(r, 2*32 + kq*8));
                bf16x8 x3 = *reinterpret_cast<const bf16x8*>(arow + SWZ(r, 3*32 + kq*8));
                f32x4 aF = {0.f,0.f,0.f,0.f};
                aF = MFMA(WF2[0],x0,aF); aF = MFMA(WF2[1],x1,aF);
                aF = MFMA(WF2[2],x2,aF); aF = MFMA(WF2[3],x3,aF);
                epiT1(aF, bb2, Sb, r, c0e);
            }
            float4 b7 = *(const float4*)(gb2 + c0e);
            float4 g3 = *(const float4*)(gw3 + c0e);
#pragma unroll
            for (int tr = 0; tr < 6; ++tr) {
                const int r = tr*16 + rl;
                const u16* arow = Bb + r*HD;
                bf16x8 x0 = *reinterpret_cast<const bf16x8*>(arow + SWZ(r, 0*32 + kq*8));
                bf16x8 x1 = *reinterpret_cast<const bf16x8*>(arow + SWZ(r, 1*32 + kq*8));
                bf16x8 x2 = *reinterpret_cast<const bf16x8*>(arow + SWZ(r, 2*32 + kq*8));
                bf16x8 x3 = *reinterpret_cast<const bf16x8*>(arow + SWZ(r, 3*32 + kq*8));
                f32x4 aG = {0.f,0.f,0.f,0.f};
                aG = MFMA(WG2[0],x0,aG); aG = MFMA(WG2[1],x1,aG);
                aG = MFMA(WG2[2],x2,aG); aG = MFMA(WG2[3],x3,aG);
                float p = tanh_f(aG[0]+b7.x)*g3.x + tanh_f(aG[1]+b7.y)*g3.y
                        + tanh_f(aG[2]+b7.z)*g3.z + tanh_f(aG[3]+b7.w)*g3.w;
                p += __shfl_xor(p, 16);
                p += __shfl_xor(p, 32);
                if (kq == 0) gpart[r*12 + wid] = p;
            }
        }
        if (doDS && tid < 384)
            head_ln4g(Db, ppd, db20, db21, 0, 0, tid, wsB + (size_t)(k-1)*384);
        __syncthreads();
        // PhC: L3f(Sb_h2f) + in-register Euler -> Ab (new state); head-E(k-1)
        if (doL1) {
            float4 b8 = *(const float4*)(fb3 + c0e);
#pragma unroll
            for (int tr = 0; tr < 6; ++tr) {
                const int r = tr*16 + rl;
                const u16* arow = Sb + r*HD;
                bf16x8 x0 = *reinterpret_cast<const bf16x8*>(arow + SWZ(r, 0*32 + kq*8));
                bf16x8 x1 = *reinterpret_cast<const bf16x8*>(arow + SWZ(r, 1*32 + kq*8));
                bf16x8 x2 = *reinterpret_cast<const bf16x8*>(arow + SWZ(r, 2*32 + kq*8));
                bf16x8 x3 = *reinterpret_cast<const bf16x8*>(arow + SWZ(r, 3*32 + kq*8));
                f32x4 aD3 = {0.f,0.f,0.f,0.f};
                aD3 = MFMA(WF3[0],x0,aD3); aD3 = MFMA(WF3[1],x1,aD3);
                aD3 = MFMA(WF3[2],x2,aD3); aD3 = MFMA(WF3[3],x3,aD3);
                const float* gp = gpart + r*12;
                float4 u0 = *reinterpret_cast<const float4*>(gp);
                float4 u1 = *reinterpret_cast<const float4*>(gp + 4);
                float gs = u0.x+u0.y+u0.z+u0.w + u1.x+u1.y+u1.z+u1.w;
                float grow = sigm_f(gs + gb3v) * SQDT_C;
                y6[tr][0] += (aD3[0]+b8.x)*DT_C + grow*nz[tr][0];
                y6[tr][1] += (aD3[1]+b8.y)*DT_C + grow*nz[tr][1];
                y6[tr][2] += (aD3[2]+b8.z)*DT_C + grow*nz[tr][2];
                y6[tr][3] += (aD3[3]+b8.w)*DT_C + grow*nz[tr][3];
                uint2 pk = { pack2(y6[tr][0], y6[tr][1]), pack2(y6[tr][2], y6[tr][3]) };
                *reinterpret_cast<uint2*>(Ab + r*HD + SWZ(r, c0e)) = pk;
            }
        }
        if (doDS && tid < 384)
            head_ln4g(Eb, pps, sb20, sb21, 1, 2, tid, wsB + (size_t)(k-1)*384);
        __syncthreads();
        // rotate state slot
        u16* t = Sb; Sb = Ab; Ab = t;
    }
}

extern "C" void kernel_launch(void* const* d_in, const int* in_sizes, int n_in,
                              void* d_out, int out_size, void* d_ws, size_t ws_size,
                              hipStream_t stream) {
    const float* lE      = (const float*)d_in[0];
    const float* gE      = (const float*)d_in[1];
    const float* noise   = (const float*)d_in[2];
    const float* aggr_w  = (const float*)d_in[3];
    const float* aggr_b  = (const float*)d_in[4];
    const float* aggr_g  = (const float*)d_in[5];
    const float* aggr_be = (const float*)d_in[6];
    const float* fw1 = (const float*)d_in[7];
    const float* fb1 = (const float*)d_in[8];
    const float* fw2 = (const float*)d_in[9];
    const float* fb2 = (const float*)d_in[10];
    const float* fw3 = (const float*)d_in[11];
    const float* fb3 = (const float*)d_in[12];
    const float* gw1 = (const float*)d_in[13];
    const float* gb1 = (const float*)d_in[14];
    const float* gw2 = (const float*)d_in[15];
    const float* gb2 = (const float*)d_in[16];
    const float* gw3 = (const float*)d_in[17];
    const float* gb3 = (const float*)d_in[18];
    const float* dw1 = (const float*)d_in[19];
    const float* db1 = (const float*)d_in[20];
    const float* dg  = (const float*)d_in[21];
    const float* dbe = (const float*)d_in[22];
    const float* dw2 = (const float*)d_in[23];
    const float* db2 = (const float*)d_in[24];
    const float* sw1 = (const float*)d_in[25];
    const float* sb1 = (const float*)d_in[26];
    const float* sg  = (const float*)d_in[27];
    const float* sbe = (const float*)d_in[28];
    const float* sw2 = (const float*)d_in[29];
    const float* sb2 = (const float*)d_in[30];
    const float* pw1 = (const float*)d_in[31];
    const float* pb1 = (const float*)d_in[32];
    const float* pg  = (const float*)d_in[33];
    const float* pbe = (const float*)d_in[34];
    const float* pw2 = (const float*)d_in[35];
    const float* pb2 = (const float*)d_in[36];
    const unsigned char* pmask = (const unsigned char*)d_in[37];
    float* outp = (float*)d_out;
    u16* wimg = (u16*)d_ws;                                  // 352 KB
    float* wsOut = (float*)((char*)d_ws + 360448);           // 256*11520 floats = 11.8 MB

    prep_w<<<dim3(64, 11), 256, 0, stream>>>(fw1, fw2, fw3, gw1, gw2, dw1, sw1,
                                             aggr_w, pw1, wimg);
    sde_fused<<<NBLKS, 512, 0, stream>>>(
        lE, gE, noise, aggr_b, aggr_g, aggr_be,
        fw1, fb1, fb2, fb3,
        gw1, gb1, gb2, gw3, gb3,
        db1, dg, dbe, dw2, db2,
        sb1, sg, sbe, sw2, sb2,
        pb1, pg, pbe, pw2, pb2,
        pmask, wimg, wsOut, outp);
    reorder_out<<<NBLKS, 384, 0, stream>>>(wsOut, outp);
}

// Round 10
// 1324.380 us; speedup vs baseline: 1.0678x; 1.0537x over previous
//
#include <hip/hip_runtime.h>

#define Adim 4096
#define HD 128
#define TSTEPS 30
#define NROWS 24576
#define RBLK 96
#define NBLKS 256           // exactly 1 block/CU, single round
#define DT_C 0.2f
#define SQDT_C 0.44721359549995794f
#define LN_EPS 1e-5f

#define PI_OFF   2949120    // 6*4096*30*4
#define MASK_OFF 2973696    // PI_OFF + 24576

typedef unsigned short u16;
typedef __bf16 bf16x8 __attribute__((ext_vector_type(8)));
typedef float f32x4 __attribute__((ext_vector_type(4)));

__device__ __forceinline__ u16 f2bf(float x){
    unsigned u = __builtin_bit_cast(unsigned, x);
    u = (u + 0x7fffu + ((u >> 16) & 1u)) >> 16;
    return (u16)u;
}
__device__ __forceinline__ float bf2f(unsigned h){
    unsigned u = (h & 0xffffu) << 16;
    return __builtin_bit_cast(float, u);
}
__device__ __forceinline__ unsigned pack2(float a, float b){
    unsigned r;
    asm("v_cvt_pk_bf16_f32 %0, %1, %2" : "=v"(r) : "v"(a), "v"(b));
    return r;
}
__device__ __forceinline__ float tanh_f(float x){
    return 1.0f - 2.0f / (1.0f + __expf(2.0f * x));
}
__device__ __forceinline__ float sigm_f(float x){
    return 1.0f / (1.0f + __expf(-x));
}
#define SWZ(r,k) ((k) ^ (((r)&7)<<3))
#define MFMA(A,B,C) __builtin_amdgcn_mfma_f32_16x16x32_bf16(A, B, C, 0, 0, 0)

// ---- per-wave weight fragments: 16 output channels per wave ----
__device__ __forceinline__ void loadW(const u16* __restrict__ img, int lane, int wid,
                                      bf16x8 W[4]) {
    const int c = wid*16 + (lane & 15);
    const int kq = lane >> 4;
#pragma unroll
    for (int kk = 0; kk < 4; ++kk)
        W[kk] = *reinterpret_cast<const bf16x8*>(img + c*HD + SWZ(c, kk*32 + kq*8));
}

// ---- per-tile epilogues (lane: row r, 4 consecutive channels c0) ----
__device__ __forceinline__ void epiT1(const f32x4& a, const float b[4],
                                      u16* dst, int r, int c0) {
    uint2 pk = { pack2(tanh_f(a[0]+b[0]), tanh_f(a[1]+b[1])),
                 pack2(tanh_f(a[2]+b[2]), tanh_f(a[3]+b[3])) };
    *reinterpret_cast<uint2*>(dst + r*HD + SWZ(r, c0)) = pk;
}
__device__ __forceinline__ void epiN1(const f32x4& a, const float b[4],
                                      u16* dst, int r, int c0) {
    uint2 pk = { pack2(a[0]+b[0], a[1]+b[1]), pack2(a[2]+b[2], a[3]+b[3]) };
    *reinterpret_cast<uint2*>(dst + r*HD + SWZ(r, c0)) = pk;
}

// ---- prologue GEMM over Xc (lda=256), 6 row tiles ----
__device__ __forceinline__ void gemmX6(const u16* __restrict__ Xc, int kBase,
                                       const u16* __restrict__ img,
                                       int lane, int wid, f32x4 acc[6], bool init) {
    bf16x8 W[4]; loadW(img, lane, wid, W);
    const int rl = lane & 15, kq = lane >> 4;
#pragma unroll
    for (int tr = 0; tr < 6; ++tr) {
        const int r = tr*16 + rl;
        const u16* arow = Xc + r*256;
        f32x4 a = init ? f32x4{0.f,0.f,0.f,0.f} : acc[tr];
#pragma unroll
        for (int kk = 0; kk < 4; ++kk) {
            bf16x8 bf = *reinterpret_cast<const bf16x8*>(arow + SWZ(r, kBase + kk*32 + kq*8));
            a = MFMA(W[kk], bf, a);
        }
        acc[tr] = a;
    }
}
__device__ __forceinline__ void epiF6(const f32x4 acc[6], const float* __restrict__ bias,
                                      float* dst, int lane, int wid) {
    const int c0 = wid*16 + ((lane>>4)<<2);
    const int rl = lane & 15;
    float4 b4 = *reinterpret_cast<const float4*>(bias + c0);
#pragma unroll
    for (int tr = 0; tr < 6; ++tr) {
        int r = tr*16 + rl;
        float4 v = { acc[tr][0]+b4.x, acc[tr][1]+b4.y, acc[tr][2]+b4.z, acc[tr][3]+b4.w };
        *reinterpret_cast<float4*>(dst + r*HD + c0) = v;
    }
}

// ---- LN + relu + 2-wide head; 4 lanes/row, 32 ch/lane, two-pass (reg-light) ----
__device__ __forceinline__ void head_ln4g(const u16* __restrict__ src,
                                          const float4* __restrict__ pp4,
                                          float b20, float b21, int elu, int off,
                                          int idx, float* __restrict__ dstRow)
{
    int row = idx >> 2, part = idx & 3;
    int c0 = part * 32;
    uint4 p[4];
#pragma unroll
    for (int u = 0; u < 4; ++u)
        p[u] = *reinterpret_cast<const uint4*>(src + row*HD + SWZ(row, c0 + u*8));
    float s = 0.f, sq = 0.f;
#pragma unroll
    for (int u = 0; u < 4; ++u) {
        float a0=bf2f(p[u].x), a1=bf2f(p[u].x>>16), a2=bf2f(p[u].y), a3=bf2f(p[u].y>>16);
        float a4=bf2f(p[u].z), a5=bf2f(p[u].z>>16), a6=bf2f(p[u].w), a7=bf2f(p[u].w>>16);
        s  += a0+a1+a2+a3+a4+a5+a6+a7;
        sq += a0*a0+a1*a1+a2*a2+a3*a3+a4*a4+a5*a5+a6*a6+a7*a7;
    }
    s += __shfl_xor(s,1); sq += __shfl_xor(sq,1);
    s += __shfl_xor(s,2); sq += __shfl_xor(sq,2);
    float mu = s * (1.f/128.f);
    float rstd = rsqrtf(sq*(1.f/128.f) - mu*mu + LN_EPS);
    float a0acc = 0.f, a1acc = 0.f;
#pragma unroll
    for (int u = 0; u < 4; ++u) {
        float vv[8] = { bf2f(p[u].x), bf2f(p[u].x>>16), bf2f(p[u].y), bf2f(p[u].y>>16),
                        bf2f(p[u].z), bf2f(p[u].z>>16), bf2f(p[u].w), bf2f(p[u].w>>16) };
#pragma unroll
        for (int i = 0; i < 8; ++i) {
            int c = c0 + u*8 + i;
            float4 pr = pp4[c ^ ((c>>4)&7)];
            float h = (vv[i]-mu)*rstd*pr.x + pr.y;
            h = fmaxf(h, 0.f);
            a0acc += h*pr.z; a1acc += h*pr.w;
        }
    }
    a0acc += __shfl_xor(a0acc,1); a1acc += __shfl_xor(a1acc,1);
    a0acc += __shfl_xor(a0acc,2); a1acc += __shfl_xor(a1acc,2);
    if (part == 0) {
        a0acc += b20; a1acc += b21;
        if (elu) {
            a0acc = (a0acc > 0.f ? a0acc : __expf(a0acc)-1.f) + 1.001f;
            a1acc = (a1acc > 0.f ? a1acc : __expf(a1acc)-1.f) + 1.001f;
        }
        *reinterpret_cast<float2*>(dstRow + row*4 + off) = make_float2(a0acc, a1acc);
    }
}

// ---------- weight image prep: f32 -> bf16, transposed, swizzled ----------
__global__ void prep_w(const float* __restrict__ fw1, const float* __restrict__ fw2,
                       const float* __restrict__ fw3, const float* __restrict__ gw1,
                       const float* __restrict__ gw2, const float* __restrict__ dw1,
                       const float* __restrict__ sw1, const float* __restrict__ aw,
                       const float* __restrict__ pw1, u16* __restrict__ ws)
{
    int img = blockIdx.y;
    int idx = blockIdx.x * 256 + threadIdx.x;
    int k = idx >> 7, j = idx & 127;
    const float* W = fw1; int sr = k;
    switch (img) {
        case 0: W = fw1; break;  case 1: W = fw2; break;  case 2: W = fw3; break;
        case 3: W = gw1; break;  case 4: W = gw2; break;
        case 5: W = dw1; break;  case 6: W = sw1; break;
        case 7: W = aw;  break;  case 8: W = aw;  sr = k + 128; break;
        case 9: W = pw1; break;  case 10: W = pw1; sr = k + 128; break;
    }
    ws[(size_t)img*16384 + j*128 + SWZ(j, k)] = f2bf(W[(size_t)sr*128 + j]);
}

// ---------- final output reorder: ws [blk][tt][row][4] -> loc_out [gr][tt][4] ----------
__global__ void reorder_out(const float* __restrict__ wsOut, float* __restrict__ outp)
{
    __shared__ float tile[11520];
    int b = blockIdx.x;
    int tid = threadIdx.x;                    // 384
    const float* src = wsOut + (size_t)b*11520;
    int row = tid >> 2, c = tid & 3;
#pragma unroll
    for (int j = 0; j < TSTEPS; ++j)
        tile[row*120 + j*4 + c] = src[j*384 + tid];
    __syncthreads();
    float* dst = outp + (size_t)b*11520;
#pragma unroll
    for (int j = 0; j < TSTEPS; ++j)
        dst[j*384 + tid] = tile[j*384 + tid];
}

// ---------- the fused persistent kernel ----------
__global__ __launch_bounds__(512, 1) void sde_fused(
    const float* __restrict__ lE, const float* __restrict__ gE,
    const float* __restrict__ noise,
    const float* __restrict__ aggr_b, const float* __restrict__ aggr_g, const float* __restrict__ aggr_be,
    const float* __restrict__ fw1, const float* __restrict__ fb1,
    const float* __restrict__ fb2, const float* __restrict__ fb3,
    const float* __restrict__ gw1, const float* __restrict__ gb1,
    const float* __restrict__ gb2, const float* __restrict__ gw3, const float* __restrict__ gb3,
    const float* __restrict__ db1, const float* __restrict__ dg, const float* __restrict__ dbe,
    const float* __restrict__ dw2, const float* __restrict__ db2,
    const float* __restrict__ sb1, const float* __restrict__ sg, const float* __restrict__ sbe,
    const float* __restrict__ sw2, const float* __restrict__ sb2,
    const float* __restrict__ pb1, const float* __restrict__ pg, const float* __restrict__ pbe,
    const float* __restrict__ pw2, const float* __restrict__ pb2,
    const unsigned char* __restrict__ pmask,
    const u16* __restrict__ wimg,
    float* __restrict__ wsOut,
    float* __restrict__ outp)
{
    // LDS: Sb@0 Ab@24K Bb@48K Cb@72K Db@96K Eb@120K (24K each, 96x128 bf16)
    //      gpart[96][8] @144K (3K) | ppd @147K (2K) | pps @149K (2K) -> 151 KB
    // prologue aliases: Xc (48K) over Sb+Ab; preLN f32 (48K) over Bb+Cb
    __shared__ __align__(16) unsigned char SMEM[154624];
    u16* Sb = (u16*)SMEM;
    u16* Ab = (u16*)(SMEM + 24576);
    u16* Bb = (u16*)(SMEM + 49152);
    u16* Cb = (u16*)(SMEM + 73728);
    u16* Db = (u16*)(SMEM + 98304);
    u16* Eb = (u16*)(SMEM + 122880);
    float* gpart = (float*)(SMEM + 147456);    // [96][8]
    float4* ppd = (float4*)(SMEM + 150528);
    float4* pps = (float4*)(SMEM + 152576);
    u16* Xc = (u16*)SMEM;
    float* preLN = (float*)(SMEM + 49152);

    const int tid  = threadIdx.x;
    const int lane = tid & 63;
    const int wid  = tid >> 6;
    const int bid  = blockIdx.x;
    const int r0   = bid * RBLK;
    const int rl   = lane & 15;
    const int kq   = lane >> 4;
    const int c0e  = wid*16 + (kq<<2);

    // -------- stage params + Xc --------
    if (tid < 128) {
        int cs = tid ^ ((tid >> 4) & 7);
        ppd[cs] = make_float4(dg[tid], dbe[tid], dw2[2*tid], dw2[2*tid+1]);
        pps[cs] = make_float4(sg[tid], sbe[tid], sw2[2*tid], sw2[2*tid+1]);
    }
#pragma unroll
    for (int i = 0; i < 6; ++i) {
        int gidx = i*512 + tid;             // 0..3071
        int r = gidx >> 5;
        int k = (gidx & 31) * 8;
        int gr = r0 + r;
        const float* src = (k < HD) ? (gE + (size_t)gr*HD + k)
                                    : (lE + (size_t)(gr & (Adim-1))*HD + (k - HD));
        float4 v0 = reinterpret_cast<const float4*>(src)[0];
        float4 v1 = reinterpret_cast<const float4*>(src)[1];
        uint4 pk = { pack2(v0.x, v0.y), pack2(v0.z, v0.w),
                     pack2(v1.x, v1.y), pack2(v1.z, v1.w) };
        *reinterpret_cast<uint4*>(Xc + r*256 + SWZ(r, k)) = pk;
    }
    __syncthreads();

    f32x4 acc6[6];

    // -------- pi head --------
    gemmX6(Xc, 0,   wimg + 10*16384, lane, wid, acc6, true);   // ge part
    gemmX6(Xc, 128, wimg + 9*16384,  lane, wid, acc6, false);  // le part
    epiF6(acc6, pb1, preLN, lane, wid);
    __syncthreads();
    if (tid < 384) {
        int row = tid >> 2, part = tid & 3;
        int c0 = part * 32;
        const float* yr = preLN + row*HD + c0;
        float v[32]; float s = 0.f, sq = 0.f;
#pragma unroll
        for (int i = 0; i < 32; ++i){ float x = yr[i]; v[i] = x; s += x; sq += x*x; }
        s += __shfl_xor(s,1); sq += __shfl_xor(sq,1);
        s += __shfl_xor(s,2); sq += __shfl_xor(sq,2);
        float mu = s*(1.f/128.f);
        float rstd = rsqrtf(sq*(1.f/128.f) - mu*mu + LN_EPS);
        float a0 = 0.f;
#pragma unroll
        for (int i = 0; i < 32; ++i){
            int cc = c0 + i;
            float h = (v[i]-mu)*rstd*pg[cc] + pbe[cc];
            a0 += fmaxf(h, 0.f) * pw2[cc];
        }
        a0 += __shfl_xor(a0,1); a0 += __shfl_xor(a0,2);
        if (part == 0) {
            int gr = r0 + row;
            outp[PI_OFF + (size_t)(gr & (Adim-1))*6 + (gr >> 12)] = a0 + pb2[0];
        }
    }
    if (tid < RBLK) {
        int gr = r0 + tid;
        if (gr < Adim) {
            const unsigned char* pm = pmask + (size_t)gr*50 + 20;
            float* o = outp + MASK_OFF + (size_t)gr*TSTEPS;
#pragma unroll
            for (int i = 0; i < TSTEPS; ++i) o[i] = pm[i] ? 0.f : 1.f;
        }
    }
    __syncthreads();

    // -------- aggr head -> h0 --------
    gemmX6(Xc, 0,   wimg + 7*16384, lane, wid, acc6, true);
    gemmX6(Xc, 128, wimg + 8*16384, lane, wid, acc6, false);
    __syncthreads();
    epiF6(acc6, aggr_b, preLN, lane, wid);
    __syncthreads();
    if (tid < 384) {               // LN + relu -> preLN (post-LN f32) + Sb (bf16)
        int row = tid >> 2, part = tid & 3;
        int c0 = part * 32;
        float* yr = preLN + row*HD + c0;
        float v[32]; float s = 0.f, sq = 0.f;
#pragma unroll
        for (int i = 0; i < 32; ++i){ float x = yr[i]; v[i] = x; s += x; sq += x*x; }
        s += __shfl_xor(s,1); sq += __shfl_xor(sq,1);
        s += __shfl_xor(s,2); sq += __shfl_xor(sq,2);
        float mu = s*(1.f/128.f);
        float rstd = rsqrtf(sq*(1.f/128.f) - mu*mu + LN_EPS);
#pragma unroll
        for (int i = 0; i < 32; ++i){
            int cc = c0 + i;
            float h = (v[i]-mu)*rstd*aggr_g[cc] + aggr_be[cc];
            v[i] = fmaxf(h, 0.f);
        }
#pragma unroll
        for (int u = 0; u < 8; ++u)
            *reinterpret_cast<float4*>(yr + u*4) = *(float4*)&v[u*4];
#pragma unroll
        for (int u = 0; u < 4; ++u) {
            uint4 pk = { pack2(v[u*8+0],v[u*8+1]), pack2(v[u*8+2],v[u*8+3]),
                         pack2(v[u*8+4],v[u*8+5]), pack2(v[u*8+6],v[u*8+7]) };
            *reinterpret_cast<uint4*>(&Sb[row*HD + SWZ(row, c0 + u*8)]) = pk;
        }
    }
    __syncthreads();

    // -------- y state into registers, LINEAR layout (24 f32/thread) --------
    float y[24];
#pragma unroll
    for (int p = 0; p < 3; ++p) {
        int flat = p*512 + tid;
        int r = flat >> 4, k0 = (flat & 15)*8;
        float4 t0 = *reinterpret_cast<const float4*>(preLN + r*HD + k0);
        float4 t1 = *reinterpret_cast<const float4*>(preLN + r*HD + k0 + 4);
        y[p*8+0]=t0.x; y[p*8+1]=t0.y; y[p*8+2]=t0.z; y[p*8+3]=t0.w;
        y[p*8+4]=t1.x; y[p*8+5]=t1.y; y[p*8+6]=t1.z; y[p*8+7]=t1.w;
    }
    __syncthreads();

    // -------- loop weights into registers (112 regs) --------
    bf16x8 WF1[4], WG1[4], WF2[4], WG2[4], WF3[4], WD1[4], WS1[4];
    loadW(wimg + 0*16384, lane, wid, WF1);
    loadW(wimg + 3*16384, lane, wid, WG1);
    loadW(wimg + 1*16384, lane, wid, WF2);
    loadW(wimg + 4*16384, lane, wid, WG2);
    loadW(wimg + 2*16384, lane, wid, WF3);
    loadW(wimg + 5*16384, lane, wid, WD1);
    loadW(wimg + 6*16384, lane, wid, WS1);

    const float db20 = db2[0], db21 = db2[1];
    const float sb20 = sb2[0], sb21 = sb2[1];
    const float gb3v = gb3[0];
    float* wsB = wsOut + (size_t)bid*TSTEPS*384;

    // -------- Euler-Maruyama scan: 4 barriers/step, tile-streamed --------
    for (int k = 0; k <= TSTEPS; ++k) {
        const bool doL1 = (k < TSTEPS), doDS = (k >= 1);
        // PhA: L1f,L1g(t_k) and D1,S1 on state Sb (shared tile reads)
        {
            float bF[4], bG[4], bD[4], bS[4];
            if (doL1) {
                float t = k * DT_C;
                float st = __sinf(t), ct = __cosf(t);
                float4 a0 = *(const float4*)(fb1 + c0e);
                float4 a1 = *(const float4*)(fw1 + 128*HD + c0e);
                float4 a2 = *(const float4*)(fw1 + 129*HD + c0e);
                float4 a3 = *(const float4*)(gb1 + c0e);
                float4 a4 = *(const float4*)(gw1 + 128*HD + c0e);
                float4 a5 = *(const float4*)(gw1 + 129*HD + c0e);
                bF[0]=a0.x+st*a1.x+ct*a2.x; bF[1]=a0.y+st*a1.y+ct*a2.y;
                bF[2]=a0.z+st*a1.z+ct*a2.z; bF[3]=a0.w+st*a1.w+ct*a2.w;
                bG[0]=a3.x+st*a4.x+ct*a5.x; bG[1]=a3.y+st*a4.y+ct*a5.y;
                bG[2]=a3.z+st*a4.z+ct*a5.z; bG[3]=a3.w+st*a4.w+ct*a5.w;
            }
            if (doDS) {
                float4 a9 = *(const float4*)(db1 + c0e);
                float4 aa = *(const float4*)(sb1 + c0e);
                bD[0]=a9.x; bD[1]=a9.y; bD[2]=a9.z; bD[3]=a9.w;
                bS[0]=aa.x; bS[1]=aa.y; bS[2]=aa.z; bS[3]=aa.w;
            }
#pragma unroll
            for (int tr = 0; tr < 6; ++tr) {
                const int r = tr*16 + rl;
                const u16* arow = Sb + r*HD;
                bf16x8 x0 = *reinterpret_cast<const bf16x8*>(arow + SWZ(r, 0*32 + kq*8));
                bf16x8 x1 = *reinterpret_cast<const bf16x8*>(arow + SWZ(r, 1*32 + kq*8));
                bf16x8 x2 = *reinterpret_cast<const bf16x8*>(arow + SWZ(r, 2*32 + kq*8));
                bf16x8 x3 = *reinterpret_cast<const bf16x8*>(arow + SWZ(r, 3*32 + kq*8));
                if (doL1) {
                    f32x4 aF = {0.f,0.f,0.f,0.f}, aG = {0.f,0.f,0.f,0.f};
                    aF = MFMA(WF1[0],x0,aF); aF = MFMA(WF1[1],x1,aF);
                    aF = MFMA(WF1[2],x2,aF); aF = MFMA(WF1[3],x3,aF);
                    aG = MFMA(WG1[0],x0,aG); aG = MFMA(WG1[1],x1,aG);
                    aG = MFMA(WG1[2],x2,aG); aG = MFMA(WG1[3],x3,aG);
                    epiT1(aF, bF, Ab, r, c0e);
                    epiT1(aG, bG, Bb, r, c0e);
                }
                if (doDS) {
                    f32x4 aD = {0.f,0.f,0.f,0.f}, aS = {0.f,0.f,0.f,0.f};
                    aD = MFMA(WD1[0],x0,aD); aD = MFMA(WD1[1],x1,aD);
                    aD = MFMA(WD1[2],x2,aD); aD = MFMA(WD1[3],x3,aD);
                    aS = MFMA(WS1[0],x0,aS); aS = MFMA(WS1[1],x1,aS);
                    aS = MFMA(WS1[2],x2,aS); aS = MFMA(WS1[3],x3,aS);
                    epiN1(aD, bD, Db, r, c0e);
                    epiN1(aS, bS, Eb, r, c0e);
                }
            }
        }
        __syncthreads();
        // PhB: L2f(Ab->Cb); L2g(Bb->gpart, fused gw3); head-D(k-1)
        if (doL1) {
            float4 b6 = *(const float4*)(fb2 + c0e);
            float bb2[4] = { b6.x, b6.y, b6.z, b6.w };
#pragma unroll
            for (int tr = 0; tr < 6; ++tr) {
                const int r = tr*16 + rl;
                const u16* arow = Ab + r*HD;
                bf16x8 x0 = *reinterpret_cast<const bf16x8*>(arow + SWZ(r, 0*32 + kq*8));
                bf16x8 x1 = *reinterpret_cast<const bf16x8*>(arow + SWZ(r, 1*32 + kq*8));
                bf16x8 x2 = *reinterpret_cast<const bf16x8*>(arow + SWZ(r, 2*32 + kq*8));
                bf16x8 x3 = *reinterpret_cast<const bf16x8*>(arow + SWZ(r, 3*32 + kq*8));
                f32x4 aF = {0.f,0.f,0.f,0.f};
                aF = MFMA(WF2[0],x0,aF); aF = MFMA(WF2[1],x1,aF);
                aF = MFMA(WF2[2],x2,aF); aF = MFMA(WF2[3],x3,aF);
                epiT1(aF, bb2, Cb, r, c0e);
            }
            float4 b7 = *(const float4*)(gb2 + c0e);
            float4 g3 = *(const float4*)(gw3 + c0e);
#pragma unroll
            for (int tr = 0; tr < 6; ++tr) {
                const int r = tr*16 + rl;
                const u16* arow = Bb + r*HD;
                bf16x8 x0 = *reinterpret_cast<const bf16x8*>(arow + SWZ(r, 0*32 + kq*8));
                bf16x8 x1 = *reinterpret_cast<const bf16x8*>(arow + SWZ(r, 1*32 + kq*8));
                bf16x8 x2 = *reinterpret_cast<const bf16x8*>(arow + SWZ(r, 2*32 + kq*8));
                bf16x8 x3 = *reinterpret_cast<const bf16x8*>(arow + SWZ(r, 3*32 + kq*8));
                f32x4 aG = {0.f,0.f,0.f,0.f};
                aG = MFMA(WG2[0],x0,aG); aG = MFMA(WG2[1],x1,aG);
                aG = MFMA(WG2[2],x2,aG); aG = MFMA(WG2[3],x3,aG);
                float p = tanh_f(aG[0]+b7.x)*g3.x + tanh_f(aG[1]+b7.y)*g3.y
                        + tanh_f(aG[2]+b7.z)*g3.z + tanh_f(aG[3]+b7.w)*g3.w;
                p += __shfl_xor(p, 16);
                p += __shfl_xor(p, 32);
                if (kq == 0) gpart[r*8 + wid] = p;
            }
        }
        if (doDS && tid < 384)
            head_ln4g(Db, ppd, db20, db21, 0, 0, tid, wsB + (size_t)(k-1)*384);
        __syncthreads();
        // PhC: L3f (Cb -> Ab, drift); head-E(k-1)
        if (doL1) {
            float4 b8 = *(const float4*)(fb3 + c0e);
            float bb3[4] = { b8.x, b8.y, b8.z, b8.w };
#pragma unroll
            for (int tr = 0; tr < 6; ++tr) {
                const int r = tr*16 + rl;
                const u16* arow = Cb + r*HD;
                bf16x8 x0 = *reinterpret_cast<const bf16x8*>(arow + SWZ(r, 0*32 + kq*8));
                bf16x8 x1 = *reinterpret_cast<const bf16x8*>(arow + SWZ(r, 1*32 + kq*8));
                bf16x8 x2 = *reinterpret_cast<const bf16x8*>(arow + SWZ(r, 2*32 + kq*8));
                bf16x8 x3 = *reinterpret_cast<const bf16x8*>(arow + SWZ(r, 3*32 + kq*8));
                f32x4 aD3 = {0.f,0.f,0.f,0.f};
                aD3 = MFMA(WF3[0],x0,aD3); aD3 = MFMA(WF3[1],x1,aD3);
                aD3 = MFMA(WF3[2],x2,aD3); aD3 = MFMA(WF3[3],x3,aD3);
                epiN1(aD3, bb3, Ab, r, c0e);
            }
        }
        if (doDS && tid < 384)
            head_ln4g(Eb, pps, sb20, sb21, 1, 2, tid, wsB + (size_t)(k-1)*384);
        __syncthreads();
        // PhD: Euler update, linear coalesced; state Sb updated in place
        if (doL1) {
            const float* nb = noise + ((size_t)k*NROWS + r0)*HD;
            f32x4 nzv[6];
#pragma unroll
            for (int p = 0; p < 3; ++p) {
                int flat = p*512 + tid;
                nzv[p*2]   = *reinterpret_cast<const f32x4*>(nb + (size_t)flat*8);
                nzv[p*2+1] = *reinterpret_cast<const f32x4*>(nb + (size_t)flat*8 + 4);
            }
#pragma unroll
            for (int p = 0; p < 3; ++p) {
                int flat = p*512 + tid;
                int r = flat >> 4, k0 = (flat & 15)*8;
                int sk = SWZ(r, k0);
                uint4 dpk = *reinterpret_cast<const uint4*>(Ab + r*HD + sk);
                const float* gp = gpart + r*8;
                float4 u0 = *reinterpret_cast<const float4*>(gp);
                float4 u1 = *reinterpret_cast<const float4*>(gp + 4);
                float gs = u0.x+u0.y+u0.z+u0.w + u1.x+u1.y+u1.z+u1.w;
                float grow = sigm_f(gs + gb3v) * SQDT_C;
                float* yy = y + p*8;
                yy[0] += bf2f(dpk.x)     * DT_C + grow*nzv[p*2][0];
                yy[1] += bf2f(dpk.x>>16) * DT_C + grow*nzv[p*2][1];
                yy[2] += bf2f(dpk.y)     * DT_C + grow*nzv[p*2][2];
                yy[3] += bf2f(dpk.y>>16) * DT_C + grow*nzv[p*2][3];
                yy[4] += bf2f(dpk.z)     * DT_C + grow*nzv[p*2+1][0];
                yy[5] += bf2f(dpk.z>>16) * DT_C + grow*nzv[p*2+1][1];
                yy[6] += bf2f(dpk.w)     * DT_C + grow*nzv[p*2+1][2];
                yy[7] += bf2f(dpk.w>>16) * DT_C + grow*nzv[p*2+1][3];
                uint4 s4 = { pack2(yy[0],yy[1]), pack2(yy[2],yy[3]),
                             pack2(yy[4],yy[5]), pack2(yy[6],yy[7]) };
                *reinterpret_cast<uint4*>(Sb + r*HD + sk) = s4;
            }
        }
        __syncthreads();
    }
}

extern "C" void kernel_launch(void* const* d_in, const int* in_sizes, int n_in,
                              void* d_out, int out_size, void* d_ws, size_t ws_size,
                              hipStream_t stream) {
    const float* lE      = (const float*)d_in[0];
    const float* gE      = (const float*)d_in[1];
    const float* noise   = (const float*)d_in[2];
    const float* aggr_w  = (const float*)d_in[3];
    const float* aggr_b  = (const float*)d_in[4];
    const float* aggr_g  = (const float*)d_in[5];
    const float* aggr_be = (const float*)d_in[6];
    const float* fw1 = (const float*)d_in[7];
    const float* fb1 = (const float*)d_in[8];
    const float* fw2 = (const float*)d_in[9];
    const float* fb2 = (const float*)d_in[10];
    const float* fw3 = (const float*)d_in[11];
    const float* fb3 = (const float*)d_in[12];
    const float* gw1 = (const float*)d_in[13];
    const float* gb1 = (const float*)d_in[14];
    const float* gw2 = (const float*)d_in[15];
    const float* gb2 = (const float*)d_in[16];
    const float* gw3 = (const float*)d_in[17];
    const float* gb3 = (const float*)d_in[18];
    const float* dw1 = (const float*)d_in[19];
    const float* db1 = (const float*)d_in[20];
    const float* dg  = (const float*)d_in[21];
    const float* dbe = (const float*)d_in[22];
    const float* dw2 = (const float*)d_in[23];
    const float* db2 = (const float*)d_in[24];
    const float* sw1 = (const float*)d_in[25];
    const float* sb1 = (const float*)d_in[26];
    const float* sg  = (const float*)d_in[27];
    const float* sbe = (const float*)d_in[28];
    const float* sw2 = (const float*)d_in[29];
    const float* sb2 = (const float*)d_in[30];
    const float* pw1 = (const float*)d_in[31];
    const float* pb1 = (const float*)d_in[32];
    const float* pg  = (const float*)d_in[33];
    const float* pbe = (const float*)d_in[34];
    const float* pw2 = (const float*)d_in[35];
    const float* pb2 = (const float*)d_in[36];
    const unsigned char* pmask = (const unsigned char*)d_in[37];
    float* outp = (float*)d_out;
    u16* wimg = (u16*)d_ws;                                  // 352 KB
    float* wsOut = (float*)((char*)d_ws + 360448);           // 256*11520 floats = 11.8 MB

    prep_w<<<dim3(64, 11), 256, 0, stream>>>(fw1, fw2, fw3, gw1, gw2, dw1, sw1,
                                             aggr_w, pw1, wimg);
    sde_fused<<<NBLKS, 512, 0, stream>>>(
        lE, gE, noise, aggr_b, aggr_g, aggr_be,
        fw1, fb1, fb2, fb3,
        gw1, gb1, gb2, gw3, gb3,
        db1, dg, dbe, dw2, db2,
        sb1, sg, sbe, sw2, sb2,
        pb1, pg, pbe, pw2, pb2,
        pmask, wimg, wsOut, outp);
    reorder_out<<<NBLKS, 384, 0, stream>>>(wsOut, outp);
}

// Round 11
// 601.426 us; speedup vs baseline: 2.3514x; 2.2021x over previous
//
#include <hip/hip_runtime.h>

#define Adim 4096
#define HD 128
#define TSTEPS 30
#define NROWS 24576
#define RBLK 32
#define NBLKS 768           // NROWS / RBLK
#define DT_C 0.2f
#define SQDT_C 0.44721359549995794f
#define LN_EPS 1e-5f

#define PI_OFF   2949120    // 6*4096*30*4
#define MASK_OFF 2973696    // PI_OFF + 24576

typedef unsigned short u16;
typedef __bf16 bf16x8 __attribute__((ext_vector_type(8)));
typedef float f32x4 __attribute__((ext_vector_type(4)));

__device__ __forceinline__ u16 f2bf(float x){
    unsigned u = __builtin_bit_cast(unsigned, x);
    u = (u + 0x7fffu + ((u >> 16) & 1u)) >> 16;
    return (u16)u;
}
__device__ __forceinline__ float bf2f(unsigned h){
    unsigned u = (h & 0xffffu) << 16;
    return __builtin_bit_cast(float, u);
}
__device__ __forceinline__ unsigned pack2(float a, float b){
    unsigned r;
    asm("v_cvt_pk_bf16_f32 %0, %1, %2" : "=v"(r) : "v"(a), "v"(b));
    return r;
}
__device__ __forceinline__ float tanh_f(float x){
    return 1.0f - 2.0f / (1.0f + __expf(2.0f * x));
}
__device__ __forceinline__ float sigm_f(float x){
    return 1.0f / (1.0f + __expf(-x));
}
#define SWZ(r,k) ((k) ^ (((r)&7)<<3))
#define MFMA(A,B,C) __builtin_amdgcn_mfma_f32_16x16x32_bf16(A, B, C, 0, 0, 0)

// ---- per-wave weight fragments: 16 output channels per wave ----
__device__ __forceinline__ void loadW(const u16* __restrict__ img, int lane, int wid,
                                      bf16x8 W[4]) {
    const int c = wid*16 + (lane & 15);
    const int kq = lane >> 4;
#pragma unroll
    for (int kk = 0; kk < 4; ++kk)
        W[kk] = *reinterpret_cast<const bf16x8*>(img + c*HD + SWZ(c, kk*32 + kq*8));
}

// ---- GEMMs (swapped): D[c][r] = sum_k W[c][k] act[r][k]; 32 rows = 2 tiles ----
__device__ __forceinline__ void gemm1(const u16* __restrict__ act, const bf16x8 (&W)[4],
                                      int lane, f32x4 acc[2]) {
    const int rl = lane & 15, kq = lane >> 4;
#pragma unroll
    for (int tr = 0; tr < 2; ++tr) {
        const int r = tr*16 + rl;
        const u16* arow = act + r*HD;
        f32x4 a = {0.f,0.f,0.f,0.f};
#pragma unroll
        for (int kk = 0; kk < 4; ++kk) {
            bf16x8 bf = *reinterpret_cast<const bf16x8*>(arow + SWZ(r, kk*32 + kq*8));
            a = MFMA(W[kk], bf, a);
        }
        acc[tr] = a;
    }
}
__device__ __forceinline__ void gemm2(const u16* __restrict__ act,
                                      const bf16x8 (&Wx)[4], const bf16x8 (&Wy)[4],
                                      int lane, f32x4 accX[2], f32x4 accY[2]) {
    const int rl = lane & 15, kq = lane >> 4;
#pragma unroll
    for (int tr = 0; tr < 2; ++tr) {
        const int r = tr*16 + rl;
        const u16* arow = act + r*HD;
        f32x4 ax = {0.f,0.f,0.f,0.f}, ay = {0.f,0.f,0.f,0.f};
#pragma unroll
        for (int kk = 0; kk < 4; ++kk) {
            bf16x8 bf = *reinterpret_cast<const bf16x8*>(arow + SWZ(r, kk*32 + kq*8));
            ax = MFMA(Wx[kk], bf, ax);
            ay = MFMA(Wy[kk], bf, ay);
        }
        accX[tr] = ax; accY[tr] = ay;
    }
}
__device__ __forceinline__ void gemm4(const u16* __restrict__ act,
                                      const bf16x8 (&W1)[4], const bf16x8 (&W2)[4],
                                      const bf16x8 (&W3)[4], const bf16x8 (&W4)[4],
                                      int lane, f32x4 a1[2], f32x4 a2[2],
                                      f32x4 a3[2], f32x4 a4[2]) {
    const int rl = lane & 15, kq = lane >> 4;
#pragma unroll
    for (int tr = 0; tr < 2; ++tr) {
        const int r = tr*16 + rl;
        const u16* arow = act + r*HD;
        f32x4 x1={0.f,0.f,0.f,0.f}, x2={0.f,0.f,0.f,0.f};
        f32x4 x3={0.f,0.f,0.f,0.f}, x4={0.f,0.f,0.f,0.f};
#pragma unroll
        for (int kk = 0; kk < 4; ++kk) {
            bf16x8 bf = *reinterpret_cast<const bf16x8*>(arow + SWZ(r, kk*32 + kq*8));
            x1 = MFMA(W1[kk], bf, x1);
            x2 = MFMA(W2[kk], bf, x2);
            x3 = MFMA(W3[kk], bf, x3);
            x4 = MFMA(W4[kk], bf, x4);
        }
        a1[tr]=x1; a2[tr]=x2; a3[tr]=x3; a4[tr]=x4;
    }
}

// ---- epilogues: lane holds 2 row-tiles, 4 consecutive channels ----
__device__ __forceinline__ void epiT(const f32x4 acc[2], const float b[4],
                                     u16* dst, int lane, int wid) {
    const int c0 = wid*16 + ((lane>>4)<<2);
    const int rl = lane & 15;
#pragma unroll
    for (int tr = 0; tr < 2; ++tr) {
        int r = tr*16 + rl;
        float v0 = tanh_f(acc[tr][0] + b[0]);
        float v1 = tanh_f(acc[tr][1] + b[1]);
        float v2 = tanh_f(acc[tr][2] + b[2]);
        float v3 = tanh_f(acc[tr][3] + b[3]);
        uint2 pk = { pack2(v0, v1), pack2(v2, v3) };
        *reinterpret_cast<uint2*>(dst + r*HD + SWZ(r, c0)) = pk;
    }
}
__device__ __forceinline__ void epiN(const f32x4 acc[2], const float b[4],
                                     u16* dst, int lane, int wid) {
    const int c0 = wid*16 + ((lane>>4)<<2);
    const int rl = lane & 15;
#pragma unroll
    for (int tr = 0; tr < 2; ++tr) {
        int r = tr*16 + rl;
        uint2 pk = { pack2(acc[tr][0]+b[0], acc[tr][1]+b[1]),
                     pack2(acc[tr][2]+b[2], acc[tr][3]+b[3]) };
        *reinterpret_cast<uint2*>(dst + r*HD + SWZ(r, c0)) = pk;
    }
}
__device__ __forceinline__ void epiF(const f32x4 acc[2], const float* __restrict__ bias,
                                     float* dst, int lane, int wid) {
    const int c0 = wid*16 + ((lane>>4)<<2);
    const int rl = lane & 15;
    float4 b4 = *reinterpret_cast<const float4*>(bias + c0);
#pragma unroll
    for (int tr = 0; tr < 2; ++tr) {
        int r = tr*16 + rl;
        float4 v = { acc[tr][0]+b4.x, acc[tr][1]+b4.y, acc[tr][2]+b4.z, acc[tr][3]+b4.w };
        *reinterpret_cast<float4*>(dst + r*HD + c0) = v;
    }
}

// ---- prologue GEMM over Xc (lda=256) ----
__device__ __forceinline__ void gemmX(const u16* __restrict__ Xc, int kBase,
                                      const u16* __restrict__ img,
                                      int lane, int wid, f32x4 acc[2], bool init) {
    bf16x8 W[4]; loadW(img, lane, wid, W);
    const int rl = lane & 15, kq = lane >> 4;
#pragma unroll
    for (int tr = 0; tr < 2; ++tr) {
        const int r = tr*16 + rl;
        const u16* arow = Xc + r*256;
        f32x4 a = init ? f32x4{0.f,0.f,0.f,0.f} : acc[tr];
#pragma unroll
        for (int kk = 0; kk < 4; ++kk) {
            bf16x8 bf = *reinterpret_cast<const bf16x8*>(arow + SWZ(r, kBase + kk*32 + kq*8));
            a = MFMA(W[kk], bf, a);
        }
        acc[tr] = a;
    }
}

// ---- LN + relu + 2-wide head; 8 lanes/row; params float4 swizzled in LDS ----
__device__ __forceinline__ void head_ln(const u16* __restrict__ src,
                                        const float4* __restrict__ pp4,
                                        float b20, float b21, int elu, int off, int idx,
                                        float* __restrict__ dstStep)
{
    int row = idx >> 3, sub = idx & 7;
    int c0 = sub * 16;
    uint4 p0 = *reinterpret_cast<const uint4*>(src + row*HD + SWZ(row, c0));
    uint4 p1 = *reinterpret_cast<const uint4*>(src + row*HD + SWZ(row, c0+8));
    float v[16];
    v[0]=bf2f(p0.x); v[1]=bf2f(p0.x>>16); v[2]=bf2f(p0.y); v[3]=bf2f(p0.y>>16);
    v[4]=bf2f(p0.z); v[5]=bf2f(p0.z>>16); v[6]=bf2f(p0.w); v[7]=bf2f(p0.w>>16);
    v[8]=bf2f(p1.x); v[9]=bf2f(p1.x>>16); v[10]=bf2f(p1.y); v[11]=bf2f(p1.y>>16);
    v[12]=bf2f(p1.z); v[13]=bf2f(p1.z>>16); v[14]=bf2f(p1.w); v[15]=bf2f(p1.w>>16);
    float s = 0.f, sq = 0.f;
#pragma unroll
    for (int i = 0; i < 16; ++i){ s += v[i]; sq += v[i]*v[i]; }
    s += __shfl_xor(s,1); sq += __shfl_xor(sq,1);
    s += __shfl_xor(s,2); sq += __shfl_xor(sq,2);
    s += __shfl_xor(s,4); sq += __shfl_xor(sq,4);
    float mu = s * (1.f/128.f);
    float rstd = rsqrtf(sq*(1.f/128.f) - mu*mu + LN_EPS);
    float a0 = 0.f, a1 = 0.f;
#pragma unroll
    for (int i = 0; i < 16; ++i){
        float4 p = pp4[(c0 + i) ^ sub];
        float h = (v[i]-mu)*rstd*p.x + p.y;
        h = fmaxf(h, 0.f);
        a0 += h * p.z; a1 += h * p.w;
    }
    a0 += __shfl_xor(a0,1); a1 += __shfl_xor(a1,1);
    a0 += __shfl_xor(a0,2); a1 += __shfl_xor(a1,2);
    a0 += __shfl_xor(a0,4); a1 += __shfl_xor(a1,4);
    if (sub == 0){
        a0 += b20; a1 += b21;
        if (elu){
            a0 = (a0 > 0.f ? a0 : __expf(a0)-1.f) + 1.001f;
            a1 = (a1 > 0.f ? a1 : __expf(a1)-1.f) + 1.001f;
        }
        *reinterpret_cast<float2*>(dstStep + row*4 + off) = make_float2(a0, a1);
    }
}

// ---------- weight image prep: f32 -> bf16, transposed, swizzled ----------
__global__ void prep_w(const float* __restrict__ fw1, const float* __restrict__ fw2,
                       const float* __restrict__ fw3, const float* __restrict__ gw1,
                       const float* __restrict__ gw2, const float* __restrict__ dw1,
                       const float* __restrict__ sw1, const float* __restrict__ aw,
                       const float* __restrict__ pw1, u16* __restrict__ ws)
{
    int img = blockIdx.y;
    int idx = blockIdx.x * 256 + threadIdx.x;   // 0..16383
    int k = idx >> 7, j = idx & 127;
    const float* W = fw1; int sr = k;
    switch (img) {
        case 0: W = fw1; break;  case 1: W = fw2; break;  case 2: W = fw3; break;
        case 3: W = gw1; break;  case 4: W = gw2; break;
        case 5: W = dw1; break;  case 6: W = sw1; break;
        case 7: W = aw;  break;  case 8: W = aw;  sr = k + 128; break;
        case 9: W = pw1; break;  case 10: W = pw1; sr = k + 128; break;
    }
    ws[(size_t)img*16384 + j*128 + SWZ(j, k)] = f2bf(W[(size_t)sr*128 + j]);
}

// ---------- final output reorder: ws [blk][tt][row][4] -> loc_out [gr][tt][4] ----------
__global__ void reorder_out(const float* __restrict__ wsOut, float* __restrict__ outp)
{
    __shared__ float tile[3840];
    int b = blockIdx.x;
    const float* src = wsOut + (size_t)b*3840;
#pragma unroll
    for (int j = 0; j < 15; ++j) {
        int idx = j*256 + threadIdx.x;        // tt*128 + row*4 + c
        int tt = idx >> 7, rc = idx & 127;
        int row = rc >> 2, c = idx & 3;
        tile[row*120 + tt*4 + c] = src[idx];
    }
    __syncthreads();
    float* dst = outp + (size_t)b*3840;
#pragma unroll
    for (int j = 0; j < 15; ++j) {
        int idx = j*256 + threadIdx.x;
        dst[idx] = tile[idx];
    }
}

// ---------- the fused persistent kernel ----------
__global__ __launch_bounds__(512, 2) void sde_fused(
    const float* __restrict__ lE, const float* __restrict__ gE,
    const float* __restrict__ noise,
    const float* __restrict__ aggr_b, const float* __restrict__ aggr_g, const float* __restrict__ aggr_be,
    const float* __restrict__ fw1, const float* __restrict__ fb1,
    const float* __restrict__ fb2, const float* __restrict__ fb3,
    const float* __restrict__ gw1, const float* __restrict__ gb1,
    const float* __restrict__ gb2, const float* __restrict__ gw3, const float* __restrict__ gb3,
    const float* __restrict__ db1, const float* __restrict__ dg, const float* __restrict__ dbe,
    const float* __restrict__ dw2, const float* __restrict__ db2,
    const float* __restrict__ sb1, const float* __restrict__ sg, const float* __restrict__ sbe,
    const float* __restrict__ sw2, const float* __restrict__ sb2,
    const float* __restrict__ pb1, const float* __restrict__ pg, const float* __restrict__ pbe,
    const float* __restrict__ pw2, const float* __restrict__ pb2,
    const unsigned char* __restrict__ pmask,
    const u16* __restrict__ wimg,
    float* __restrict__ wsOut,
    float* __restrict__ outp)
{
    // LDS (54272 B): Sb@0 Ab@8K Bb@16K Cb@24K Db@32K Eb@40K (8K each)
    //   gpart[32][8] @48K (1K) | ppd @49K (2K) | pps @51K (2K)
    // prologue aliases: Xc (16K) over Db+Eb; preLN f32 (16K) over Ab+Bb
    __shared__ __align__(16) unsigned char SMEM[54272];
    u16*  Sb    = (u16*)SMEM;
    u16*  Ab    = (u16*)(SMEM + 8192);
    u16*  Bb    = (u16*)(SMEM + 16384);
    u16*  Cb    = (u16*)(SMEM + 24576);
    u16*  Db    = (u16*)(SMEM + 32768);
    u16*  Eb    = (u16*)(SMEM + 40960);
    float* gpart = (float*)(SMEM + 49152);     // [32][8]
    float4* ppd = (float4*)(SMEM + 50176);
    float4* pps = (float4*)(SMEM + 52224);
    u16*  Xc    = (u16*)(SMEM + 32768);
    float* preLN = (float*)(SMEM + 8192);

    const int tid  = threadIdx.x;
    const int lane = tid & 63;
    const int wid  = tid >> 6;
    const int bid  = blockIdx.x;
    const int r0   = bid * RBLK;
    const int rl   = lane & 15;
    const int c0e  = wid*16 + ((lane>>4)<<2);

    // -------- stage params + Xc --------
    if (tid < 128) {
        int cs = tid ^ ((tid >> 4) & 7);
        ppd[cs] = make_float4(dg[tid], dbe[tid], dw2[2*tid], dw2[2*tid+1]);
        pps[cs] = make_float4(sg[tid], sbe[tid], sw2[2*tid], sw2[2*tid+1]);
    }
#pragma unroll
    for (int i = 0; i < 2; ++i) {
        int gidx = i*512 + tid;
        int r = gidx >> 5;
        int k = (gidx & 31) * 8;
        int gr = r0 + r;
        const float* src = (k < HD) ? (gE + (size_t)gr*HD + k)
                                    : (lE + (size_t)(gr & (Adim-1))*HD + (k - HD));
        float4 v0 = reinterpret_cast<const float4*>(src)[0];
        float4 v1 = reinterpret_cast<const float4*>(src)[1];
        uint4 pk = { pack2(v0.x, v0.y), pack2(v0.z, v0.w),
                     pack2(v1.x, v1.y), pack2(v1.z, v1.w) };
        *reinterpret_cast<uint4*>(Xc + r*256 + SWZ(r, k)) = pk;
    }
    __syncthreads();

    f32x4 acc[2];

    // -------- pi head --------
    gemmX(Xc, 0,   wimg + 10*16384, lane, wid, acc, true);
    gemmX(Xc, 128, wimg + 9*16384,  lane, wid, acc, false);
    epiF(acc, pb1, preLN, lane, wid);
    __syncthreads();
    {
        int row = tid >> 4, sub = tid & 15;
        int c0 = sub * 8;
        const float* yr = preLN + row*HD + c0;
        float v[8]; float s = 0.f, sq = 0.f;
#pragma unroll
        for (int i = 0; i < 8; ++i){ float x = yr[i]; v[i] = x; s += x; sq += x*x; }
        s += __shfl_xor(s,1); sq += __shfl_xor(sq,1);
        s += __shfl_xor(s,2); sq += __shfl_xor(sq,2);
        s += __shfl_xor(s,4); sq += __shfl_xor(sq,4);
        s += __shfl_xor(s,8); sq += __shfl_xor(sq,8);
        float mu = s*(1.f/128.f);
        float rstd = rsqrtf(sq*(1.f/128.f) - mu*mu + LN_EPS);
        float a0 = 0.f;
#pragma unroll
        for (int i = 0; i < 8; ++i){
            int cc = c0 + i;
            float h = (v[i]-mu)*rstd*pg[cc] + pbe[cc];
            a0 += fmaxf(h, 0.f) * pw2[cc];
        }
        a0 += __shfl_xor(a0,1); a0 += __shfl_xor(a0,2);
        a0 += __shfl_xor(a0,4); a0 += __shfl_xor(a0,8);
        if (sub == 0) {
            int gr = r0 + row;
            outp[PI_OFF + (size_t)(gr & (Adim-1))*6 + (gr >> 12)] = a0 + pb2[0];
        }
    }
    if (tid < RBLK) {
        int gr = r0 + tid;
        if (gr < Adim) {
            const unsigned char* pm = pmask + (size_t)gr*50 + 20;
            float* o = outp + MASK_OFF + (size_t)gr*TSTEPS;
#pragma unroll
            for (int i = 0; i < TSTEPS; ++i) o[i] = pm[i] ? 0.f : 1.f;
        }
    }
    __syncthreads();

    // -------- aggr head -> h0 --------
    gemmX(Xc, 0,   wimg + 7*16384, lane, wid, acc, true);
    gemmX(Xc, 128, wimg + 8*16384, lane, wid, acc, false);
    __syncthreads();
    epiF(acc, aggr_b, preLN, lane, wid);
    __syncthreads();
    {
        int row = tid >> 4, sub = tid & 15;
        int c0 = sub * 8;
        float* yr = preLN + row*HD + c0;
        float v[8]; float s = 0.f, sq = 0.f;
#pragma unroll
        for (int i = 0; i < 8; ++i){ float x = yr[i]; v[i] = x; s += x; sq += x*x; }
        s += __shfl_xor(s,1); sq += __shfl_xor(sq,1);
        s += __shfl_xor(s,2); sq += __shfl_xor(sq,2);
        s += __shfl_xor(s,4); sq += __shfl_xor(sq,4);
        s += __shfl_xor(s,8); sq += __shfl_xor(sq,8);
        float mu = s*(1.f/128.f);
        float rstd = rsqrtf(sq*(1.f/128.f) - mu*mu + LN_EPS);
#pragma unroll
        for (int i = 0; i < 8; ++i){
            int cc = c0 + i;
            float h = (v[i]-mu)*rstd*aggr_g[cc] + aggr_be[cc];
            v[i] = fmaxf(h, 0.f);
        }
        // post-LN h0 back to preLN (f32) + Sb (bf16)
        *reinterpret_cast<float4*>(yr)     = *(float4*)&v[0];
        *reinterpret_cast<float4*>(yr + 4) = *(float4*)&v[4];
        uint4 pk = { pack2(v[0],v[1]), pack2(v[2],v[3]),
                     pack2(v[4],v[5]), pack2(v[6],v[7]) };
        *reinterpret_cast<uint4*>(&Sb[row*HD + SWZ(row, c0)]) = pk;
    }
    __syncthreads();

    // -------- y state into registers, MFMA D-layout (rows {rl,16+rl}, cols c0e..+3) --------
    f32x4 yA = *reinterpret_cast<const f32x4*>(preLN + rl*HD + c0e);
    f32x4 yB = *reinterpret_cast<const f32x4*>(preLN + (16+rl)*HD + c0e);
    __syncthreads();

    // -------- loop weights into registers (112 regs) --------
    bf16x8 WF1[4], WG1[4], WF2[4], WG2[4], WF3[4], WD1[4], WS1[4];
    loadW(wimg + 0*16384, lane, wid, WF1);
    loadW(wimg + 3*16384, lane, wid, WG1);
    loadW(wimg + 1*16384, lane, wid, WF2);
    loadW(wimg + 4*16384, lane, wid, WG2);
    loadW(wimg + 2*16384, lane, wid, WF3);
    loadW(wimg + 5*16384, lane, wid, WD1);
    loadW(wimg + 6*16384, lane, wid, WS1);

    const float db20 = db2[0], db21 = db2[1];
    const float sb20 = sb2[0], sb21 = sb2[1];
    const float gb3v = gb3[0];
    float* wsB = wsOut + (size_t)bid*TSTEPS*128;

    f32x4 nzA, nzB;

    // -------- Euler-Maruyama scan: 3 barriers/step --------
    for (int k = 0; k <= TSTEPS; ++k) {
        const bool doL1 = (k < TSTEPS), doDS = (k >= 1);
        // PhA: noise prefetch (D-layout); L1f,L1g(t_k) and D1,S1 on Sb
        if (doL1) {
            const float* nb = noise + ((size_t)k*NROWS + r0)*HD;
            nzA = *reinterpret_cast<const f32x4*>(nb + (size_t)rl*HD + c0e);
            nzB = *reinterpret_cast<const f32x4*>(nb + (size_t)(16+rl)*HD + c0e);
        }
        {
            float bF[4], bG[4], bD[4], bS[4];
            if (doL1) {
                float t = k * DT_C;
                float st = __sinf(t), ct = __cosf(t);
                float4 a0 = *(const float4*)(fb1 + c0e);
                float4 a1 = *(const float4*)(fw1 + 128*HD + c0e);
                float4 a2 = *(const float4*)(fw1 + 129*HD + c0e);
                float4 a3 = *(const float4*)(gb1 + c0e);
                float4 a4 = *(const float4*)(gw1 + 128*HD + c0e);
                float4 a5 = *(const float4*)(gw1 + 129*HD + c0e);
                bF[0]=a0.x+st*a1.x+ct*a2.x; bF[1]=a0.y+st*a1.y+ct*a2.y;
                bF[2]=a0.z+st*a1.z+ct*a2.z; bF[3]=a0.w+st*a1.w+ct*a2.w;
                bG[0]=a3.x+st*a4.x+ct*a5.x; bG[1]=a3.y+st*a4.y+ct*a5.y;
                bG[2]=a3.z+st*a4.z+ct*a5.z; bG[3]=a3.w+st*a4.w+ct*a5.w;
            }
            if (doDS) {
                float4 a9 = *(const float4*)(db1 + c0e);
                float4 aa = *(const float4*)(sb1 + c0e);
                bD[0]=a9.x; bD[1]=a9.y; bD[2]=a9.z; bD[3]=a9.w;
                bS[0]=aa.x; bS[1]=aa.y; bS[2]=aa.z; bS[3]=aa.w;
            }
            if (doL1 && doDS) {
                f32x4 aF[2], aG[2], aD[2], aS[2];
                gemm4(Sb, WF1, WG1, WD1, WS1, lane, aF, aG, aD, aS);
                epiT(aF, bF, Ab, lane, wid);
                epiT(aG, bG, Bb, lane, wid);
                epiN(aD, bD, Db, lane, wid);
                epiN(aS, bS, Eb, lane, wid);
            } else if (doL1) {
                f32x4 aF[2], aG[2];
                gemm2(Sb, WF1, WG1, lane, aF, aG);
                epiT(aF, bF, Ab, lane, wid);
                epiT(aG, bG, Bb, lane, wid);
            } else {
                f32x4 aD[2], aS[2];
                gemm2(Sb, WD1, WS1, lane, aD, aS);
                epiN(aD, bD, Db, lane, wid);
                epiN(aS, bS, Eb, lane, wid);
            }
        }
        __syncthreads();
        // PhB: L2f(Ab->Cb); L2g(Bb->gpart, fused tanh+gw3); heads(k-1) direct->global
        if (doL1) {
            float4 b6 = *(const float4*)(fb2 + c0e);
            float bb2[4] = { b6.x, b6.y, b6.z, b6.w };
            f32x4 a1[2];
            gemm1(Ab, WF2, lane, a1);
            epiT(a1, bb2, Cb, lane, wid);
            float4 b7 = *(const float4*)(gb2 + c0e);
            float4 g3 = *(const float4*)(gw3 + c0e);
            gemm1(Bb, WG2, lane, a1);
            float p0 = tanh_f(a1[0][0]+b7.x)*g3.x + tanh_f(a1[0][1]+b7.y)*g3.y
                     + tanh_f(a1[0][2]+b7.z)*g3.z + tanh_f(a1[0][3]+b7.w)*g3.w;
            float p1 = tanh_f(a1[1][0]+b7.x)*g3.x + tanh_f(a1[1][1]+b7.y)*g3.y
                     + tanh_f(a1[1][2]+b7.z)*g3.z + tanh_f(a1[1][3]+b7.w)*g3.w;
            p0 += __shfl_xor(p0, 16); p0 += __shfl_xor(p0, 32);
            p1 += __shfl_xor(p1, 16); p1 += __shfl_xor(p1, 32);
            if ((lane >> 4) == 0) {
                gpart[rl*8 + wid]      = p0;
                gpart[(16+rl)*8 + wid] = p1;
            }
        }
        if (doDS) {
            float* dstStep = wsB + (size_t)(k-1)*128;
            if (tid < 256) head_ln(Db, ppd, db20, db21, 0, 0, tid, dstStep);
            else           head_ln(Eb, pps, sb20, sb21, 1, 2, tid-256, dstStep);
        }
        __syncthreads();
        // PhC: L3f(Cb) + gpart reduce + in-register Euler (D-layout) -> Sb
        if (doL1) {
            f32x4 a1[2];
            gemm1(Cb, WF3, lane, a1);
            float4 b8 = *(const float4*)(fb3 + c0e);
#pragma unroll
            for (int tr = 0; tr < 2; ++tr) {
                int r = tr*16 + rl;
                const float* gp = gpart + r*8;
                float4 u0 = *reinterpret_cast<const float4*>(gp);
                float4 u1 = *reinterpret_cast<const float4*>(gp + 4);
                float gs = u0.x+u0.y+u0.z+u0.w + u1.x+u1.y+u1.z+u1.w;
                float grow = sigm_f(gs + gb3v) * SQDT_C;
                f32x4& yy = (tr == 0) ? yA : yB;
                const f32x4& nz = (tr == 0) ? nzA : nzB;
                yy[0] += (a1[tr][0]+b8.x)*DT_C + grow*nz[0];
                yy[1] += (a1[tr][1]+b8.y)*DT_C + grow*nz[1];
                yy[2] += (a1[tr][2]+b8.z)*DT_C + grow*nz[2];
                yy[3] += (a1[tr][3]+b8.w)*DT_C + grow*nz[3];
                uint2 pk = { pack2(yy[0], yy[1]), pack2(yy[2], yy[3]) };
                *reinterpret_cast<uint2*>(Sb + r*HD + SWZ(r, c0e)) = pk;
            }
        }
        __syncthreads();
    }
}

extern "C" void kernel_launch(void* const* d_in, const int* in_sizes, int n_in,
                              void* d_out, int out_size, void* d_ws, size_t ws_size,
                              hipStream_t stream) {
    const float* lE      = (const float*)d_in[0];
    const float* gE      = (const float*)d_in[1];
    const float* noise   = (const float*)d_in[2];
    const float* aggr_w  = (const float*)d_in[3];
    const float* aggr_b  = (const float*)d_in[4];
    const float* aggr_g  = (const float*)d_in[5];
    const float* aggr_be = (const float*)d_in[6];
    const float* fw1 = (const float*)d_in[7];
    const float* fb1 = (const float*)d_in[8];
    const float* fw2 = (const float*)d_in[9];
    const float* fb2 = (const float*)d_in[10];
    const float* fw3 = (const float*)d_in[11];
    const float* fb3 = (const float*)d_in[12];
    const float* gw1 = (const float*)d_in[13];
    const float* gb1 = (const float*)d_in[14];
    const float* gw2 = (const float*)d_in[15];
    const float* gb2 = (const float*)d_in[16];
    const float* gw3 = (const float*)d_in[17];
    const float* gb3 = (const float*)d_in[18];
    const float* dw1 = (const float*)d_in[19];
    const float* db1 = (const float*)d_in[20];
    const float* dg  = (const float*)d_in[21];
    const float* dbe = (const float*)d_in[22];
    const float* dw2 = (const float*)d_in[23];
    const float* db2 = (const float*)d_in[24];
    const float* sw1 = (const float*)d_in[25];
    const float* sb1 = (const float*)d_in[26];
    const float* sg  = (const float*)d_in[27];
    const float* sbe = (const float*)d_in[28];
    const float* sw2 = (const float*)d_in[29];
    const float* sb2 = (const float*)d_in[30];
    const float* pw1 = (const float*)d_in[31];
    const float* pb1 = (const float*)d_in[32];
    const float* pg  = (const float*)d_in[33];
    const float* pbe = (const float*)d_in[34];
    const float* pw2 = (const float*)d_in[35];
    const float* pb2 = (const float*)d_in[36];
    const unsigned char* pmask = (const unsigned char*)d_in[37];
    float* outp = (float*)d_out;
    u16* wimg = (u16*)d_ws;                                  // 352 KB
    float* wsOut = (float*)((char*)d_ws + 360448);           // 768*3840 floats = 11.8 MB

    prep_w<<<dim3(64, 11), 256, 0, stream>>>(fw1, fw2, fw3, gw1, gw2, dw1, sw1,
                                             aggr_w, pw1, wimg);
    sde_fused<<<NBLKS, 512, 0, stream>>>(
        lE, gE, noise, aggr_b, aggr_g, aggr_be,
        fw1, fb1, fb2, fb3,
        gw1, gb1, gb2, gw3, gb3,
        db1, dg, dbe, dw2, db2,
        sb1, sg, sbe, sw2, sb2,
        pb1, pg, pbe, pw2, pb2,
        pmask, wimg, wsOut, outp);
    reorder_out<<<NBLKS, 256, 0, stream>>>(wsOut, outp);
}